// Round 1
// baseline (1333.129 us; speedup 1.0000x reference)
//
#include <hip/hip_runtime.h>
#include <cstdint>

// SpatioTemporalGAT: GAT(per b,t) -> LSTM over T -> Linear
// B=T=32, N=256, F_IN=F_OUT=32, H=256
constexpr int B_ = 32, T_ = 32, N_ = 256, FIN = 32, FOUT = 32, H_ = 256;
constexpr int IN_ = N_ * FOUT;   // 8192
constexpr int G4  = 4 * H_;      // 1024 (gate rows, order i,f,g,o)
constexpr int BT  = B_ * T_;     // 1024
#define NEG_SLOPE 0.2f

// ---- bf16 pack helpers (RTNE; inputs are bounded, no NaN/Inf concerns) ----
__device__ inline uint32_t f2bf_hi(float f) {
    uint32_t u = __float_as_uint(f);
    return (u + 0x7fffu + ((u >> 16) & 1u)) & 0xffff0000u;  // bf16 bits in HIGH half
}
__device__ inline uint32_t packbf2(float lo, float hi) {
    return (f2bf_hi(lo) >> 16) | f2bf_hi(hi);               // lo in low16, hi in high16
}

// =====================================================================
// K1: fused GAT for one (b,t). Lanes = target node i, loop over source j
// so adj[bt, j, i] is coalesced across the wave. No max-subtraction:
// e = leaky(s_dst+s_src) is O(10), exp() safe in fp32.
// =====================================================================
__global__ __launch_bounds__(256) void gat_kernel(
    const float* __restrict__ x, const float* __restrict__ adj,
    const float* __restrict__ W, const float* __restrict__ a_src,
    const float* __restrict__ a_dst, const float* __restrict__ gat_b,
    float* __restrict__ seq)
{
    const int bt = blockIdx.x;
    const int i  = threadIdx.x;
    __shared__ float Ws[FIN * FOUT];   // [f][k]
    __shared__ float hs[N_ * 36];      // stride 36: 16B-aligned f4 reads, write banks ok
    __shared__ float ssrc[N_];
    __shared__ float asv[FOUT], adv[FOUT], gbv[FOUT];

    for (int t = i; t < FIN * FOUT; t += 256) Ws[t] = W[t];
    if (i < FOUT) { asv[i] = a_src[i]; adv[i] = a_dst[i]; gbv[i] = gat_b[i]; }

    // x row into regs (per-thread contiguous)
    float xr[FIN];
    const float* xrow = x + ((size_t)bt * N_ + i) * FIN;
    #pragma unroll
    for (int f4 = 0; f4 < FIN / 4; ++f4) {
        float4 v = reinterpret_cast<const float4*>(xrow)[f4];
        xr[4*f4] = v.x; xr[4*f4+1] = v.y; xr[4*f4+2] = v.z; xr[4*f4+3] = v.w;
    }
    __syncthreads();

    // h[i,:] = x[i,:] @ W  (Ws reads are wave-broadcast, conflict-free)
    float hr[FOUT];
    #pragma unroll
    for (int k4 = 0; k4 < FOUT / 4; ++k4) {
        float ax = 0.f, ay = 0.f, az = 0.f, aw = 0.f;
        #pragma unroll
        for (int f = 0; f < FIN; ++f) {
            float4 w4 = *reinterpret_cast<const float4*>(&Ws[f*FOUT + 4*k4]);
            ax += xr[f]*w4.x; ay += xr[f]*w4.y; az += xr[f]*w4.z; aw += xr[f]*w4.w;
        }
        hr[4*k4] = ax; hr[4*k4+1] = ay; hr[4*k4+2] = az; hr[4*k4+3] = aw;
    }
    float ss = 0.f, sd = 0.f;
    #pragma unroll
    for (int k = 0; k < FOUT; ++k) { ss += hr[k]*asv[k]; sd += hr[k]*adv[k]; }
    #pragma unroll
    for (int k = 0; k < FOUT; ++k) hs[i*36 + k] = hr[k];
    ssrc[i] = ss;
    __syncthreads();

    // softmax over sources j (mask: adj[j,i]!=0 or j==i) + weighted sum of h[j,:]
    float acc[FOUT];
    #pragma unroll
    for (int k = 0; k < FOUT; ++k) acc[k] = 0.f;
    float l = 0.f;
    const float* adjcol = adj + (size_t)bt * N_ * N_ + i;
    for (int j = 0; j < N_; ++j) {
        float a = adjcol[(size_t)j * N_];     // coalesced across lanes
        float e = sd + ssrc[j];
        e = e > 0.f ? e : NEG_SLOPE * e;
        if ((a != 0.f) || (j == i)) {
            float p = __expf(e);
            l += p;
            #pragma unroll
            for (int k4 = 0; k4 < FOUT/4; ++k4) {
                float4 h4 = *reinterpret_cast<const float4*>(&hs[j*36 + 4*k4]); // broadcast
                acc[4*k4]   += p * h4.x;
                acc[4*k4+1] += p * h4.y;
                acc[4*k4+2] += p * h4.z;
                acc[4*k4+3] += p * h4.w;
            }
        }
    }
    float inv = 1.f / l;
    float* orow = seq + (size_t)bt * IN_ + i * FOUT;
    #pragma unroll
    for (int k4 = 0; k4 < FOUT/4; ++k4) {
        float4 v;
        v.x = acc[4*k4]  *inv + gbv[4*k4];
        v.y = acc[4*k4+1]*inv + gbv[4*k4+1];
        v.z = acc[4*k4+2]*inv + gbv[4*k4+2];
        v.w = acc[4*k4+3]*inv + gbv[4*k4+3];
        reinterpret_cast<float4*>(orow)[k4] = v;
    }
}

// =====================================================================
// K2: fp32 GEMM  G[bt][n] += seq[bt][k] * W_ih[n][k]   (M=N=1024, K=8192)
// 64x64 tile, BK=32, split-K=4 via atomicAdd (G pre-zeroed).
// LDS k-major with XOR swizzle (m4 ^= kc): transposed stores 2-way (free),
// compute reads broadcast / BW-floor b128.
// =====================================================================
__global__ __launch_bounds__(256) void gemm_in_kernel(
    const float* __restrict__ A, const float* __restrict__ Bw,
    float* __restrict__ G)
{
    __shared__ float As[32 * 64];
    __shared__ float Bs[32 * 64];
    const int tid = threadIdx.x;
    const int tx = tid & 15, ty = tid >> 4;
    const int m0 = blockIdx.y * 64, n0 = blockIdx.x * 64;
    const int kbase = blockIdx.z * 2048;
    float acc[4][4] = {{0.f}};

    for (int kt = 0; kt < 2048; kt += 32) {
        #pragma unroll
        for (int r = 0; r < 2; ++r) {
            int q = tid + r * 256;
            int row = q >> 3, kc = q & 7;
            const float4 av = *reinterpret_cast<const float4*>(
                A + (size_t)(m0 + row) * IN_ + kbase + kt + kc * 4);
            const float4 bv = *reinterpret_cast<const float4*>(
                Bw + (size_t)(n0 + row) * IN_ + kbase + kt + kc * 4);
            int sw = (((row >> 2) ^ kc) << 2) | (row & 3);
            const float* ap = reinterpret_cast<const float*>(&av);
            const float* bp = reinterpret_cast<const float*>(&bv);
            #pragma unroll
            for (int u = 0; u < 4; ++u) {
                As[(kc*4 + u) * 64 + sw] = ap[u];
                Bs[(kc*4 + u) * 64 + sw] = bp[u];
            }
        }
        __syncthreads();
        #pragma unroll
        for (int k = 0; k < 32; ++k) {
            int kc3 = (k >> 2) & 7;
            float4 a4 = *reinterpret_cast<const float4*>(&As[k*64 + ((ty ^ kc3) << 2)]);
            float4 b4 = *reinterpret_cast<const float4*>(&Bs[k*64 + ((tx ^ kc3) << 2)]);
            const float* aa = reinterpret_cast<const float*>(&a4);
            const float* bb = reinterpret_cast<const float*>(&b4);
            #pragma unroll
            for (int mi = 0; mi < 4; ++mi)
                #pragma unroll
                for (int ni = 0; ni < 4; ++ni)
                    acc[mi][ni] += aa[mi] * bb[ni];
        }
        __syncthreads();
    }
    #pragma unroll
    for (int mi = 0; mi < 4; ++mi) {
        float* grow = G + (size_t)(m0 + ty*4 + mi) * G4 + n0 + tx*4;
        #pragma unroll
        for (int ni = 0; ni < 4; ++ni)
            atomicAdd(grow + ni, acc[mi][ni]);
    }
}

// =====================================================================
// K2b: pre-pack W_hh cols 220..255 to bf16x2 (L2-resident stream buffer for K3)
// layout pw[(j>>1)*2048 + 2*g + (j&1)], j in [0,18), u = 220+2j
// =====================================================================
__global__ void pack_whh_kernel(const float* __restrict__ Whh, uint32_t* __restrict__ pw)
{
    int g = blockIdx.x * 256 + threadIdx.x;  // 0..1023
    const float* wrow = Whh + (size_t)g * H_;
    #pragma unroll
    for (int j = 0; j < 18; ++j) {
        float2 v = *reinterpret_cast<const float2*>(wrow + 220 + 2*j);
        pw[(j >> 1) * 2048 + 2*g + (j & 1)] = packbf2(v.x, v.y);
    }
}

// =====================================================================
// K3: LSTM recurrence + output linear. One block per batch b, 1024 threads
// (thread = gate row g). W_hh row as bf16x2: 96 packs in VGPRs (u<192),
// 14 packs in LDS (u 192..219, 56KB), 18 packs streamed from pw (u 220..255).
// h, c, accumulation all fp32 (only weights are bf16: err ~2e-4 << 9.4e-3).
// =====================================================================
__global__ __launch_bounds__(1024) void lstm_kernel(
    const float* __restrict__ G, const float* __restrict__ Whh,
    const uint32_t* __restrict__ pw,
    const float* __restrict__ b_ih, const float* __restrict__ b_hh,
    const float* __restrict__ Wo, const float* __restrict__ bo,
    float* __restrict__ out)
{
    const int b = blockIdx.x;
    const int g = threadIdx.x;
    __shared__ float hs[H_];
    __shared__ float gsh[G4];
    __shared__ uint32_t wl[7 * 2048];   // 14 packs x 1024 gates = 56KB

    const float* wrow = Whh + (size_t)g * H_;
    uint32_t w2r[96];
    #pragma unroll
    for (int j = 0; j < 96; ++j) {
        float2 v = *reinterpret_cast<const float2*>(wrow + 2*j);
        w2r[j] = packbf2(v.x, v.y);
    }
    #pragma unroll
    for (int j = 0; j < 14; ++j) {
        float2 v = *reinterpret_cast<const float2*>(wrow + 192 + 2*j);
        wl[(j >> 1) * 2048 + 2*g + (j & 1)] = packbf2(v.x, v.y);
    }
    if (g < H_) hs[g] = 0.f;
    float c = 0.f;
    const float bias = b_ih[g] + b_hh[g];
    const float* Gb = G + (size_t)b * T_ * G4 + g;
    __syncthreads();

    for (int t = 0; t < T_; ++t) {
        float acc = bias + Gb[(size_t)t * G4];
        #pragma unroll
        for (int j4 = 0; j4 < 48; ++j4) {          // u 0..191 from VGPR packs
            float4 h4 = *reinterpret_cast<const float4*>(&hs[4*j4]);
            uint32_t p0 = w2r[2*j4], p1 = w2r[2*j4+1];
            acc += __uint_as_float(p0 << 16)          * h4.x
                 + __uint_as_float(p0 & 0xffff0000u)  * h4.y
                 + __uint_as_float(p1 << 16)          * h4.z
                 + __uint_as_float(p1 & 0xffff0000u)  * h4.w;
        }
        #pragma unroll
        for (int j4 = 0; j4 < 7; ++j4) {           // u 192..219 from LDS packs
            float4 h4 = *reinterpret_cast<const float4*>(&hs[192 + 4*j4]);
            uint2 pp = *reinterpret_cast<const uint2*>(&wl[j4*2048 + 2*g]);
            acc += __uint_as_float(pp.x << 16)         * h4.x
                 + __uint_as_float(pp.x & 0xffff0000u) * h4.y
                 + __uint_as_float(pp.y << 16)         * h4.z
                 + __uint_as_float(pp.y & 0xffff0000u) * h4.w;
        }
        #pragma unroll
        for (int j4 = 0; j4 < 9; ++j4) {           // u 220..255 streamed (L2)
            float4 h4 = *reinterpret_cast<const float4*>(&hs[220 + 4*j4]);
            uint2 pp = *reinterpret_cast<const uint2*>(&pw[j4*2048 + 2*g]);
            acc += __uint_as_float(pp.x << 16)         * h4.x
                 + __uint_as_float(pp.x & 0xffff0000u) * h4.y
                 + __uint_as_float(pp.y << 16)         * h4.z
                 + __uint_as_float(pp.y & 0xffff0000u) * h4.w;
        }
        gsh[g] = acc;
        __syncthreads();
        if (g < H_) {
            float xi = gsh[g], xf = gsh[H_ + g], xg = gsh[2*H_ + g], xo = gsh[3*H_ + g];
            float si = 1.f / (1.f + __expf(-xi));
            float sf = 1.f / (1.f + __expf(-xf));
            float so = 1.f / (1.f + __expf(-xo));
            float eg = __expf(2.f * xg);
            float tg = 1.f - 2.f / (eg + 1.f);
            c = sf * c + si * tg;
            float ec = __expf(2.f * c);
            float th = 1.f - 2.f / (ec + 1.f);
            hs[g] = so * th;
        }
        __syncthreads();
    }
    // fused output linear: out[b,n] = h_last . Wo[n,:] + bo[n]
    if (g < N_) {
        const float* worow = Wo + (size_t)g * H_;
        float o = bo[g];
        #pragma unroll
        for (int u4 = 0; u4 < H_/4; ++u4) {
            float4 w4 = *reinterpret_cast<const float4*>(worow + 4*u4);
            float4 h4 = *reinterpret_cast<const float4*>(&hs[4*u4]);
            o += w4.x*h4.x + w4.y*h4.y + w4.z*h4.z + w4.w*h4.w;
        }
        out[(size_t)b * N_ + g] = o;
    }
}

extern "C" void kernel_launch(void* const* d_in, const int* in_sizes, int n_in,
                              void* d_out, int out_size, void* d_ws, size_t ws_size,
                              hipStream_t stream) {
    const float* x     = (const float*)d_in[0];
    const float* adj   = (const float*)d_in[1];
    const float* W     = (const float*)d_in[2];
    const float* a_src = (const float*)d_in[3];
    const float* a_dst = (const float*)d_in[4];
    const float* gat_b = (const float*)d_in[5];
    const float* W_ih  = (const float*)d_in[6];
    const float* W_hh  = (const float*)d_in[7];
    const float* b_ih  = (const float*)d_in[8];
    const float* b_hh  = (const float*)d_in[9];
    const float* Wo    = (const float*)d_in[10];
    const float* bo    = (const float*)d_in[11];
    float* out = (float*)d_out;

    // workspace: seq [1024][8192] f32 (32MB) | G [1024][1024] f32 (4MB) | pw 72KB
    float* seq = (float*)d_ws;
    float* G   = seq + (size_t)BT * IN_;
    uint32_t* pw = (uint32_t*)(G + (size_t)BT * G4);

    hipMemsetAsync(G, 0, (size_t)BT * G4 * sizeof(float), stream);
    pack_whh_kernel<<<dim3(4), dim3(256), 0, stream>>>(W_hh, pw);
    gat_kernel<<<dim3(BT), dim3(256), 0, stream>>>(x, adj, W, a_src, a_dst, gat_b, seq);
    dim3 g2(G4 / 64, BT / 64, 4);
    gemm_in_kernel<<<g2, dim3(256), 0, stream>>>(seq, W_ih, G);
    lstm_kernel<<<dim3(B_), dim3(1024), 0, stream>>>(G, W_hh, pw, b_ih, b_hh, Wo, bo, out);
}

// Round 2
// 645.660 us; speedup vs baseline: 2.0648x; 2.0648x over previous
//
#include <hip/hip_runtime.h>
#include <cstdint>

constexpr int B_ = 32, T_ = 32, N_ = 256, FIN = 32, FOUT = 32, H_ = 256;
constexpr int IN_ = N_ * FOUT;   // 8192
constexpr int G4  = 4 * H_;      // 1024
constexpr int BT  = B_ * T_;     // 1024
#define NEG_SLOPE 0.2f

typedef _Float16 half8 __attribute__((ext_vector_type(8)));
typedef _Float16 h2    __attribute__((ext_vector_type(2)));
typedef float    f4    __attribute__((ext_vector_type(4)));

__device__ inline uint32_t pkh2(float a, float b) {
    union { uint32_t u; _Float16 h[2]; } z;
    z.h[0] = (_Float16)a; z.h[1] = (_Float16)b; return z.u;
}
__device__ inline float f16lo(uint32_t u){ union{uint32_t u; _Float16 h[2];} z; z.u=u; return (float)z.h[0]; }
__device__ inline float f16hi(uint32_t u){ union{uint32_t u; _Float16 h[2];} z; z.u=u; return (float)z.h[1]; }

__device__ inline float dot2f(uint32_t w, uint32_t h, float acc) {
    union { uint32_t u; h2 v; } a, b; a.u = w; b.u = h;
#if __has_builtin(__builtin_amdgcn_fdot2)
    return __builtin_amdgcn_fdot2(a.v, b.v, acc, false);
#else
    return acc + (float)a.v.x * (float)b.v.x + (float)a.v.y * (float)b.v.y;
#endif
}

__device__ inline void gload16(const void* g, void* l) {
    __builtin_amdgcn_global_load_lds(
        (const __attribute__((address_space(1))) void*)g,
        (__attribute__((address_space(3))) void*)l, 16, 0, 0);
}

// =====================================================================
// K1: fused GAT per (b,t). Lanes = target i; loop sources j (coalesced adj
// column reads). Output written as f16 hi + f16 lo (feeds f16x2 MFMA GEMM).
// =====================================================================
__global__ __launch_bounds__(256) void gat_kernel(
    const float* __restrict__ x, const float* __restrict__ adj,
    const float* __restrict__ W, const float* __restrict__ a_src,
    const float* __restrict__ a_dst, const float* __restrict__ gat_b,
    _Float16* __restrict__ seq_hi, _Float16* __restrict__ seq_lo)
{
    const int bt = blockIdx.x;
    const int i  = threadIdx.x;
    __shared__ float Ws[FIN * FOUT];
    __shared__ float hs[N_ * 36];
    __shared__ float ssrc[N_];
    __shared__ float asv[FOUT], adv[FOUT], gbv[FOUT];

    for (int t = i; t < FIN * FOUT; t += 256) Ws[t] = W[t];
    if (i < FOUT) { asv[i] = a_src[i]; adv[i] = a_dst[i]; gbv[i] = gat_b[i]; }

    float xr[FIN];
    const float* xrow = x + ((size_t)bt * N_ + i) * FIN;
    #pragma unroll
    for (int f4i = 0; f4i < FIN / 4; ++f4i) {
        float4 v = reinterpret_cast<const float4*>(xrow)[f4i];
        xr[4*f4i] = v.x; xr[4*f4i+1] = v.y; xr[4*f4i+2] = v.z; xr[4*f4i+3] = v.w;
    }
    __syncthreads();

    float hr[FOUT];
    #pragma unroll
    for (int k4 = 0; k4 < FOUT / 4; ++k4) {
        float ax = 0.f, ay = 0.f, az = 0.f, aw = 0.f;
        #pragma unroll
        for (int f = 0; f < FIN; ++f) {
            float4 w4 = *reinterpret_cast<const float4*>(&Ws[f*FOUT + 4*k4]);
            ax += xr[f]*w4.x; ay += xr[f]*w4.y; az += xr[f]*w4.z; aw += xr[f]*w4.w;
        }
        hr[4*k4] = ax; hr[4*k4+1] = ay; hr[4*k4+2] = az; hr[4*k4+3] = aw;
    }
    float ss = 0.f, sd = 0.f;
    #pragma unroll
    for (int k = 0; k < FOUT; ++k) { ss += hr[k]*asv[k]; sd += hr[k]*adv[k]; }
    #pragma unroll
    for (int k = 0; k < FOUT; ++k) hs[i*36 + k] = hr[k];
    ssrc[i] = ss;
    __syncthreads();

    float acc[FOUT];
    #pragma unroll
    for (int k = 0; k < FOUT; ++k) acc[k] = 0.f;
    float l = 0.f;
    const float* adjcol = adj + (size_t)bt * N_ * N_ + i;
    #pragma unroll 4
    for (int j = 0; j < N_; ++j) {
        float a = adjcol[(size_t)j * N_];
        float e = sd + ssrc[j];
        e = e > 0.f ? e : NEG_SLOPE * e;
        float p = ((a != 0.f) || (j == i)) ? __expf(e) : 0.f;
        l += p;
        #pragma unroll
        for (int k4 = 0; k4 < FOUT/4; ++k4) {
            float4 h4 = *reinterpret_cast<const float4*>(&hs[j*36 + 4*k4]);
            acc[4*k4]   += p * h4.x;
            acc[4*k4+1] += p * h4.y;
            acc[4*k4+2] += p * h4.z;
            acc[4*k4+3] += p * h4.w;
        }
    }
    float inv = 1.f / l;
    _Float16 vhi[FOUT], vlo[FOUT];
    #pragma unroll
    for (int k = 0; k < FOUT; ++k) {
        float v = acc[k]*inv + gbv[k];
        _Float16 h = (_Float16)v;
        vhi[k] = h;
        vlo[k] = (_Float16)(v - (float)h);
    }
    _Float16* ohi = seq_hi + (size_t)bt * IN_ + i * FOUT;
    _Float16* olo = seq_lo + (size_t)bt * IN_ + i * FOUT;
    #pragma unroll
    for (int k8 = 0; k8 < FOUT/8; ++k8) {
        *reinterpret_cast<half8*>(ohi + 8*k8) = *reinterpret_cast<half8*>(&vhi[8*k8]);
        *reinterpret_cast<half8*>(olo + 8*k8) = *reinterpret_cast<half8*>(&vlo[8*k8]);
    }
}

// =====================================================================
// K2a: W_ih f32 -> f16
// =====================================================================
__global__ __launch_bounds__(256) void pack_wih_kernel(
    const float* __restrict__ Wih, _Float16* __restrict__ out)
{
    int idx = (blockIdx.x * 256 + threadIdx.x) * 8;
    float4 v0 = *reinterpret_cast<const float4*>(Wih + idx);
    float4 v1 = *reinterpret_cast<const float4*>(Wih + idx + 4);
    half8 o;
    o[0]=(_Float16)v0.x; o[1]=(_Float16)v0.y; o[2]=(_Float16)v0.z; o[3]=(_Float16)v0.w;
    o[4]=(_Float16)v1.x; o[5]=(_Float16)v1.y; o[6]=(_Float16)v1.z; o[7]=(_Float16)v1.w;
    *reinterpret_cast<half8*>(out + idx) = o;
}

// =====================================================================
// K2b: W_hh -> f16x2 packs. p<100 pack-major pwv[p][g]; p>=100 uint4-grouped
// pws[(p-100)>>2][g][(p-100)&3] for coalesced dwordx4 streaming in K3.
// =====================================================================
__global__ __launch_bounds__(256) void pack_whh_kernel(
    const float* __restrict__ Whh, uint32_t* __restrict__ pwv, uint32_t* __restrict__ pws)
{
    int g = blockIdx.x * 256 + threadIdx.x;
    const float* row = Whh + (size_t)g * H_;
    #pragma unroll
    for (int p = 0; p < 128; ++p) {
        float2 v = *reinterpret_cast<const float2*>(row + 2*p);
        uint32_t u = pkh2(v.x, v.y);
        if (p < 100) pwv[p * 1024 + g] = u;
        else { int pp = p - 100; pws[(pp >> 2) * 4096 + g * 4 + (pp & 3)] = u; }
    }
}

// =====================================================================
// K3: f16 MFMA GEMM  G[m=bt][n=gate] += (Ahi+Alo)[m][k] * B[n][k]
// 128x128 tile, BK=32, 2 precision passes, split-K=8 (atomicAdd, G zeroed).
// =====================================================================
__global__ __launch_bounds__(256, 4) void gemm_kernel(
    const _Float16* __restrict__ Ahi, const _Float16* __restrict__ Alo,
    const _Float16* __restrict__ Bh, float* __restrict__ G)
{
    __shared__ __align__(16) _Float16 As[128 * 32];
    __shared__ __align__(16) _Float16 Bs[128 * 32];
    const int t = threadIdx.x;
    const int L = t & 63, w = t >> 6;
    const int wm = w & 1, wn = w >> 1;
    const int m0 = blockIdx.y * 128, n0 = blockIdx.x * 128;
    const int kz = blockIdx.z * 1024;

    f4 acc[4][4] = {};
    const int q0 = t, q1 = t + 256;
    const int row0 = q0 >> 2, kc0 = q0 & 3;
    const int row1 = q1 >> 2, kc1 = q1 & 3;
    const int la = (L & 15) * 32 + (L >> 4) * 8;

    #pragma unroll
    for (int pass = 0; pass < 2; ++pass) {
        const _Float16* Ab = pass ? Alo : Ahi;
        const _Float16* A0 = Ab + (size_t)(m0 + row0) * IN_ + kz + kc0 * 8;
        const _Float16* A1 = Ab + (size_t)(m0 + row1) * IN_ + kz + kc1 * 8;
        const _Float16* B0 = Bh + (size_t)(n0 + row0) * IN_ + kz + kc0 * 8;
        const _Float16* B1 = Bh + (size_t)(n0 + row1) * IN_ + kz + kc1 * 8;
        for (int kb = 0; kb < 1024; kb += 32) {
            __syncthreads();
            gload16(A0 + kb, &As[q0 * 8]);
            gload16(A1 + kb, &As[q1 * 8]);
            gload16(B0 + kb, &Bs[q0 * 8]);
            gload16(B1 + kb, &Bs[q1 * 8]);
            __syncthreads();
            half8 af[4], bf[4];
            #pragma unroll
            for (int mi = 0; mi < 4; ++mi)
                af[mi] = *reinterpret_cast<const half8*>(&As[(wm*64 + mi*16) * 32 + la]);
            #pragma unroll
            for (int ni = 0; ni < 4; ++ni)
                bf[ni] = *reinterpret_cast<const half8*>(&Bs[(wn*64 + ni*16) * 32 + la]);
            #pragma unroll
            for (int mi = 0; mi < 4; ++mi)
                #pragma unroll
                for (int ni = 0; ni < 4; ++ni)
                    acc[mi][ni] = __builtin_amdgcn_mfma_f32_16x16x32_f16(
                        af[mi], bf[ni], acc[mi][ni], 0, 0, 0);
        }
    }
    const int cn = n0 + wn * 64 + (L & 15);
    const int rm = m0 + wm * 64 + (L >> 4) * 4;
    #pragma unroll
    for (int mi = 0; mi < 4; ++mi)
        #pragma unroll
        for (int ni = 0; ni < 4; ++ni)
            #pragma unroll
            for (int r = 0; r < 4; ++r)
                atomicAdd(&G[(size_t)(rm + mi*16 + r) * G4 + cn + ni*16], acc[mi][ni][r]);
}

// =====================================================================
// K4: LSTM recurrence + output linear. Block per b, thread = gate row.
// Weight row (128 f16x2 packs): 88 VGPR + 12 LDS + 28 streamed (uint4).
// v_dot2_f32_f16 accumulate; h round-tripped as f16x2 in LDS.
// =====================================================================
__global__ __launch_bounds__(1024, 4) void lstm_kernel(
    const float* __restrict__ G, const uint32_t* __restrict__ pwv,
    const uint32_t* __restrict__ pws,
    const float* __restrict__ b_ih, const float* __restrict__ b_hh,
    const float* __restrict__ Wo, const float* __restrict__ bo,
    float* __restrict__ out)
{
    const int b = blockIdx.x;
    const int g = threadIdx.x;
    __shared__ __align__(16) uint32_t hsp[128];      // h as f16x2
    __shared__ float gsh[G4];
    __shared__ __align__(16) uint32_t wl[3 * 4096];  // 12 packs x 1024, uint4-grouped

    uint32_t wv[88];
    #pragma unroll
    for (int p = 0; p < 88; ++p) wv[p] = pwv[p * 1024 + g];
    #pragma unroll
    for (int p = 88; p < 100; ++p) {
        int pp = p - 88;
        wl[(pp >> 2) * 4096 + g * 4 + (pp & 3)] = pwv[p * 1024 + g];
    }
    if (g < 128) hsp[g] = 0u;
    float c = 0.f;
    const float bias = b_ih[g] + b_hh[g];
    const float* Gb = G + (size_t)b * T_ * G4 + g;
    const uint4* pws4 = reinterpret_cast<const uint4*>(pws);
    const uint4* wl4  = reinterpret_cast<const uint4*>(wl);
    const uint4* hsp4 = reinterpret_cast<const uint4*>(hsp);
    __syncthreads();

    for (int t = 0; t < T_; ++t) {
        float acc = bias + Gb[(size_t)t * G4];
        #pragma unroll
        for (int q = 0; q < 32; ++q) {
            uint4 h4 = hsp4[q];                       // broadcast
            uint4 w4;
            if (q < 22) {
                w4.x = wv[4*q]; w4.y = wv[4*q+1]; w4.z = wv[4*q+2]; w4.w = wv[4*q+3];
            } else if (q < 25) {
                w4 = wl4[(q - 22) * 1024 + g];
            } else {
                w4 = pws4[(q - 25) * 1024 + g];       // coalesced L2 stream
            }
            acc = dot2f(w4.x, h4.x, acc);
            acc = dot2f(w4.y, h4.y, acc);
            acc = dot2f(w4.z, h4.z, acc);
            acc = dot2f(w4.w, h4.w, acc);
        }
        gsh[g] = acc;
        __syncthreads();
        if (g < H_) {
            float xi = gsh[g], xf = gsh[H_ + g], xg = gsh[2*H_ + g], xo = gsh[3*H_ + g];
            float si = 1.f / (1.f + __expf(-xi));
            float sf = 1.f / (1.f + __expf(-xf));
            float so = 1.f / (1.f + __expf(-xo));
            float eg = __expf(2.f * xg);
            float tg = 1.f - 2.f / (eg + 1.f);
            c = sf * c + si * tg;
            float ec = __expf(2.f * c);
            float th = 1.f - 2.f / (ec + 1.f);
            reinterpret_cast<_Float16*>(hsp)[g] = (_Float16)(so * th);
        }
        __syncthreads();
    }
    if (g < N_) {
        const float* worow = Wo + (size_t)g * H_;
        float o = bo[g];
        #pragma unroll
        for (int q = 0; q < 32; ++q) {
            uint4 hq = hsp4[q];
            float4 w0 = *reinterpret_cast<const float4*>(worow + q*8);
            float4 w1 = *reinterpret_cast<const float4*>(worow + q*8 + 4);
            o += w0.x * f16lo(hq.x) + w0.y * f16hi(hq.x)
               + w0.z * f16lo(hq.y) + w0.w * f16hi(hq.y)
               + w1.x * f16lo(hq.z) + w1.y * f16hi(hq.z)
               + w1.z * f16lo(hq.w) + w1.w * f16hi(hq.w);
        }
        out[(size_t)b * N_ + g] = o;
    }
}

extern "C" void kernel_launch(void* const* d_in, const int* in_sizes, int n_in,
                              void* d_out, int out_size, void* d_ws, size_t ws_size,
                              hipStream_t stream) {
    const float* x     = (const float*)d_in[0];
    const float* adj   = (const float*)d_in[1];
    const float* W     = (const float*)d_in[2];
    const float* a_src = (const float*)d_in[3];
    const float* a_dst = (const float*)d_in[4];
    const float* gat_b = (const float*)d_in[5];
    const float* W_ih  = (const float*)d_in[6];
    const float* W_hh  = (const float*)d_in[7];
    const float* b_ih  = (const float*)d_in[8];
    const float* b_hh  = (const float*)d_in[9];
    const float* Wo    = (const float*)d_in[10];
    const float* bo    = (const float*)d_in[11];
    float* out = (float*)d_out;

    // ws: seq_hi 16MB | seq_lo 16MB | wih_h 16MB | G 4MB | pwv 400KB | pws 112KB
    _Float16* seq_hi = (_Float16*)d_ws;
    _Float16* seq_lo = seq_hi + (size_t)BT * IN_;
    _Float16* wih_h  = seq_lo + (size_t)BT * IN_;
    float*    G      = (float*)(wih_h + (size_t)G4 * IN_);
    uint32_t* pwv    = (uint32_t*)(G + (size_t)BT * G4);
    uint32_t* pws    = pwv + 100 * 1024;

    hipMemsetAsync(G, 0, (size_t)BT * G4 * sizeof(float), stream);
    pack_whh_kernel<<<dim3(4), dim3(256), 0, stream>>>(W_hh, pwv, pws);
    pack_wih_kernel<<<dim3(4096), dim3(256), 0, stream>>>(W_ih, wih_h);
    gat_kernel<<<dim3(BT), dim3(256), 0, stream>>>(x, adj, W, a_src, a_dst, gat_b, seq_hi, seq_lo);
    gemm_kernel<<<dim3(8, 8, 8), dim3(256), 0, stream>>>(seq_hi, seq_lo, wih_h, G);
    lstm_kernel<<<dim3(B_), dim3(1024), 0, stream>>>(G, pwv, pws, b_ih, b_hh, Wo, bo, out);
}

// Round 3
// 612.292 us; speedup vs baseline: 2.1773x; 1.0545x over previous
//
#include <hip/hip_runtime.h>
#include <cstdint>

constexpr int B_ = 32, T_ = 32, N_ = 256, FIN = 32, FOUT = 32, H_ = 256;
constexpr int IN_ = N_ * FOUT;   // 8192
constexpr int G4  = 4 * H_;      // 1024
constexpr int BT  = B_ * T_;     // 1024
#define NEG_SLOPE 0.2f

typedef _Float16 half8 __attribute__((ext_vector_type(8)));
typedef _Float16 h2    __attribute__((ext_vector_type(2)));
typedef float    f4    __attribute__((ext_vector_type(4)));

__device__ inline uint32_t pkh2(float a, float b) {
    union { uint32_t u; _Float16 h[2]; } z;
    z.h[0] = (_Float16)a; z.h[1] = (_Float16)b; return z.u;
}
__device__ inline float f16lo(uint32_t u){ union{uint32_t u; _Float16 h[2];} z; z.u=u; return (float)z.h[0]; }
__device__ inline float f16hi(uint32_t u){ union{uint32_t u; _Float16 h[2];} z; z.u=u; return (float)z.h[1]; }

__device__ inline float dot2f(uint32_t w, uint32_t h, float acc) {
    union { uint32_t u; h2 v; } a, b; a.u = w; b.u = h;
#if __has_builtin(__builtin_amdgcn_fdot2)
    return __builtin_amdgcn_fdot2(a.v, b.v, acc, false);
#else
    return acc + (float)a.v.x * (float)b.v.x + (float)a.v.y * (float)b.v.y;
#endif
}

__device__ inline void gload16(const void* g, void* l) {
    __builtin_amdgcn_global_load_lds(
        (const __attribute__((address_space(1))) void*)g,
        (__attribute__((address_space(3))) void*)l, 16, 0, 0);
}

// =====================================================================
// K1: fused GAT per (b,t). Lanes = target i; loop j-PAIRS with h packed
// f16x2 in LDS (hpp[q][k], stride 36 -> aligned b128 broadcast reads,
// one-time 8-way write conflicts). Inner: 8 b128 + 32 dot2 per 2 sources.
// =====================================================================
__global__ __launch_bounds__(256) void gat_kernel(
    const float* __restrict__ x, const float* __restrict__ adj,
    const float* __restrict__ W, const float* __restrict__ a_src,
    const float* __restrict__ a_dst, const float* __restrict__ gat_b,
    _Float16* __restrict__ seq)
{
    const int bt = blockIdx.x;
    const int i  = threadIdx.x;
    __shared__ float Ws[FIN * FOUT];
    __shared__ __align__(16) uint32_t hpp[128 * 36];  // [q][k] f16x2 pairs
    __shared__ float ssrc[N_];
    __shared__ float asv[FOUT], adv[FOUT], gbv[FOUT];

    for (int t = i; t < FIN * FOUT; t += 256) Ws[t] = W[t];
    if (i < FOUT) { asv[i] = a_src[i]; adv[i] = a_dst[i]; gbv[i] = gat_b[i]; }

    float xr[FIN];
    const float* xrow = x + ((size_t)bt * N_ + i) * FIN;
    #pragma unroll
    for (int f4i = 0; f4i < FIN / 4; ++f4i) {
        float4 v = reinterpret_cast<const float4*>(xrow)[f4i];
        xr[4*f4i] = v.x; xr[4*f4i+1] = v.y; xr[4*f4i+2] = v.z; xr[4*f4i+3] = v.w;
    }
    __syncthreads();

    float hr[FOUT];
    #pragma unroll
    for (int k4 = 0; k4 < FOUT / 4; ++k4) {
        float ax = 0.f, ay = 0.f, az = 0.f, aw = 0.f;
        #pragma unroll
        for (int f = 0; f < FIN; ++f) {
            float4 w4 = *reinterpret_cast<const float4*>(&Ws[f*FOUT + 4*k4]);
            ax += xr[f]*w4.x; ay += xr[f]*w4.y; az += xr[f]*w4.z; aw += xr[f]*w4.w;
        }
        hr[4*k4] = ax; hr[4*k4+1] = ay; hr[4*k4+2] = az; hr[4*k4+3] = aw;
    }
    float ss = 0.f, sd = 0.f;
    #pragma unroll
    for (int k = 0; k < FOUT; ++k) { ss += hr[k]*asv[k]; sd += hr[k]*adv[k]; }
    // pack h[i][k] into pair slot (q=i/2, half=i&1)
    _Float16* hp16 = reinterpret_cast<_Float16*>(hpp);
    #pragma unroll
    for (int k = 0; k < FOUT; ++k)
        hp16[(i >> 1) * 72 + 2*k + (i & 1)] = (_Float16)hr[k];
    ssrc[i] = ss;
    __syncthreads();

    float acc[FOUT];
    #pragma unroll
    for (int k = 0; k < FOUT; ++k) acc[k] = 0.f;
    float l = 0.f;
    const float* adjcol = adj + (size_t)bt * N_ * N_ + i;
    #pragma unroll 2
    for (int q = 0; q < 128; ++q) {
        const int j0 = 2*q, j1 = 2*q + 1;
        float a0 = adjcol[(size_t)j0 * N_];
        float a1 = adjcol[(size_t)j1 * N_];
        float e0 = sd + ssrc[j0]; e0 = e0 > 0.f ? e0 : NEG_SLOPE * e0;
        float e1 = sd + ssrc[j1]; e1 = e1 > 0.f ? e1 : NEG_SLOPE * e1;
        float p0 = ((a0 != 0.f) || (j0 == i)) ? __expf(e0) : 0.f;
        float p1 = ((a1 != 0.f) || (j1 == i)) ? __expf(e1) : 0.f;
        l += p0 + p1;
        uint32_t pk = pkh2(p0, p1);
        const uint32_t* hq = &hpp[q * 36];
        #pragma unroll
        for (int k4 = 0; k4 < 8; ++k4) {
            uint4 hv = *reinterpret_cast<const uint4*>(&hq[4*k4]);  // broadcast
            acc[4*k4+0] = dot2f(pk, hv.x, acc[4*k4+0]);
            acc[4*k4+1] = dot2f(pk, hv.y, acc[4*k4+1]);
            acc[4*k4+2] = dot2f(pk, hv.z, acc[4*k4+2]);
            acc[4*k4+3] = dot2f(pk, hv.w, acc[4*k4+3]);
        }
    }
    float inv = 1.f / l;
    _Float16 vh[FOUT];
    #pragma unroll
    for (int k = 0; k < FOUT; ++k)
        vh[k] = (_Float16)(acc[k]*inv + gbv[k]);
    _Float16* orow = seq + (size_t)bt * IN_ + i * FOUT;
    #pragma unroll
    for (int k8 = 0; k8 < FOUT/8; ++k8)
        *reinterpret_cast<half8*>(orow + 8*k8) = *reinterpret_cast<half8*>(&vh[8*k8]);
}

// =====================================================================
// K2a: W_ih f32 -> f16
// =====================================================================
__global__ __launch_bounds__(256) void pack_wih_kernel(
    const float* __restrict__ Wih, _Float16* __restrict__ out)
{
    int idx = (blockIdx.x * 256 + threadIdx.x) * 8;
    float4 v0 = *reinterpret_cast<const float4*>(Wih + idx);
    float4 v1 = *reinterpret_cast<const float4*>(Wih + idx + 4);
    half8 o;
    o[0]=(_Float16)v0.x; o[1]=(_Float16)v0.y; o[2]=(_Float16)v0.z; o[3]=(_Float16)v0.w;
    o[4]=(_Float16)v1.x; o[5]=(_Float16)v1.y; o[6]=(_Float16)v1.z; o[7]=(_Float16)v1.w;
    *reinterpret_cast<half8*>(out + idx) = o;
}

// =====================================================================
// K2b: W_hh -> f16x2 packs. p<64 pack-major (VGPR load in K4);
// p 64..87 -> pwl uint4-grouped (bulk-copied to LDS); p 88..127 -> pws
// uint4-grouped (streamed from L2 each timestep).
// =====================================================================
__global__ __launch_bounds__(256) void pack_whh_kernel(
    const float* __restrict__ Whh, uint32_t* __restrict__ pwv,
    uint32_t* __restrict__ pwl, uint32_t* __restrict__ pws)
{
    int g = blockIdx.x * 256 + threadIdx.x;
    const float* row = Whh + (size_t)g * H_;
    #pragma unroll
    for (int p = 0; p < 128; ++p) {
        float2 v = *reinterpret_cast<const float2*>(row + 2*p);
        uint32_t u = pkh2(v.x, v.y);
        if (p < 64) pwv[p * 1024 + g] = u;
        else if (p < 88) { int pp = p - 64; pwl[(pp >> 2) * 4096 + g * 4 + (pp & 3)] = u; }
        else            { int pp = p - 88; pws[(pp >> 2) * 4096 + g * 4 + (pp & 3)] = u; }
    }
}

// =====================================================================
// K3: f16 MFMA GEMM (single pass)  G[m=bt][n] += A[m][k] * B[n][k]
// 128x128 tile, BK=32, split-K=8 (atomicAdd, G zeroed).
// =====================================================================
__global__ __launch_bounds__(256, 4) void gemm_kernel(
    const _Float16* __restrict__ A, const _Float16* __restrict__ Bh,
    float* __restrict__ G)
{
    __shared__ __align__(16) _Float16 As[128 * 32];
    __shared__ __align__(16) _Float16 Bs[128 * 32];
    const int t = threadIdx.x;
    const int L = t & 63, w = t >> 6;
    const int wm = w & 1, wn = w >> 1;
    const int m0 = blockIdx.y * 128, n0 = blockIdx.x * 128;
    const int kz = blockIdx.z * 1024;

    f4 acc[4][4] = {};
    const int q0 = t, q1 = t + 256;
    const int row0 = q0 >> 2, kc0 = q0 & 3;
    const int row1 = q1 >> 2, kc1 = q1 & 3;
    const int la = (L & 15) * 32 + (L >> 4) * 8;

    const _Float16* A0 = A + (size_t)(m0 + row0) * IN_ + kz + kc0 * 8;
    const _Float16* A1 = A + (size_t)(m0 + row1) * IN_ + kz + kc1 * 8;
    const _Float16* B0 = Bh + (size_t)(n0 + row0) * IN_ + kz + kc0 * 8;
    const _Float16* B1 = Bh + (size_t)(n0 + row1) * IN_ + kz + kc1 * 8;
    for (int kb = 0; kb < 1024; kb += 32) {
        __syncthreads();
        gload16(A0 + kb, &As[q0 * 8]);
        gload16(A1 + kb, &As[q1 * 8]);
        gload16(B0 + kb, &Bs[q0 * 8]);
        gload16(B1 + kb, &Bs[q1 * 8]);
        __syncthreads();
        half8 af[4], bf[4];
        #pragma unroll
        for (int mi = 0; mi < 4; ++mi)
            af[mi] = *reinterpret_cast<const half8*>(&As[(wm*64 + mi*16) * 32 + la]);
        #pragma unroll
        for (int ni = 0; ni < 4; ++ni)
            bf[ni] = *reinterpret_cast<const half8*>(&Bs[(wn*64 + ni*16) * 32 + la]);
        #pragma unroll
        for (int mi = 0; mi < 4; ++mi)
            #pragma unroll
            for (int ni = 0; ni < 4; ++ni)
                acc[mi][ni] = __builtin_amdgcn_mfma_f32_16x16x32_f16(
                    af[mi], bf[ni], acc[mi][ni], 0, 0, 0);
    }
    const int cn = n0 + wn * 64 + (L & 15);
    const int rm = m0 + wm * 64 + (L >> 4) * 4;
    #pragma unroll
    for (int mi = 0; mi < 4; ++mi)
        #pragma unroll
        for (int ni = 0; ni < 4; ++ni)
            #pragma unroll
            for (int r = 0; r < 4; ++r)
                atomicAdd(&G[(size_t)(rm + mi*16 + r) * G4 + cn + ni*16], acc[mi][ni][r]);
}

// =====================================================================
// K4: LSTM recurrence + output linear. Block per b, thread = gate row.
// W_hh row (128 f16x2 packs): 64 VGPR + 24 LDS (96KB) + 40 streamed.
// 1024-thr block => hard 128-VGPR cap: 64-pack split fits without spill.
// =====================================================================
__global__ __launch_bounds__(1024) void lstm_kernel(
    const float* __restrict__ G, const uint32_t* __restrict__ pwv,
    const uint32_t* __restrict__ pwl, const uint32_t* __restrict__ pws,
    const float* __restrict__ b_ih, const float* __restrict__ b_hh,
    const float* __restrict__ Wo, const float* __restrict__ bo,
    float* __restrict__ out)
{
    const int b = blockIdx.x;
    const int g = threadIdx.x;
    __shared__ __align__(16) uint32_t hsp[128];      // h as f16x2
    __shared__ float gsh[G4];
    __shared__ __align__(16) uint32_t wl[6 * 4096];  // 24 packs x 1024 = 96KB

    uint32_t wv[64];
    #pragma unroll
    for (int p = 0; p < 64; ++p) wv[p] = pwv[p * 1024 + g];
    {   // bulk-copy 24 packs to LDS (uint4, coalesced, conflict-free)
        const uint4* s = reinterpret_cast<const uint4*>(pwl);
        uint4* d = reinterpret_cast<uint4*>(wl);
        #pragma unroll
        for (int r = 0; r < 6; ++r) d[r * 1024 + g] = s[r * 1024 + g];
    }
    if (g < 128) hsp[g] = 0u;
    float c = 0.f;
    const float bias = b_ih[g] + b_hh[g];
    const float* Gb = G + (size_t)b * T_ * G4 + g;
    const uint4* pws4 = reinterpret_cast<const uint4*>(pws);
    const uint4* wl4  = reinterpret_cast<const uint4*>(wl);
    const uint4* hsp4 = reinterpret_cast<const uint4*>(hsp);
    float gnext = Gb[0];
    __syncthreads();

    for (int t = 0; t < T_; ++t) {
        float acc = bias + gnext;
        if (t + 1 < T_) gnext = Gb[(size_t)(t + 1) * G4];  // prefetch next timestep
        #pragma unroll
        for (int q = 0; q < 32; ++q) {
            uint4 h4 = hsp4[q];                       // broadcast
            uint4 w4;
            if (q < 16) {
                w4.x = wv[4*q]; w4.y = wv[4*q+1]; w4.z = wv[4*q+2]; w4.w = wv[4*q+3];
            } else if (q < 22) {
                w4 = wl4[(q - 16) * 1024 + g];        // LDS b128, conflict-free
            } else {
                w4 = pws4[(q - 22) * 1024 + g];       // coalesced L2 stream
            }
            acc = dot2f(w4.x, h4.x, acc);
            acc = dot2f(w4.y, h4.y, acc);
            acc = dot2f(w4.z, h4.z, acc);
            acc = dot2f(w4.w, h4.w, acc);
        }
        gsh[g] = acc;
        __syncthreads();
        if (g < H_) {
            float xi = gsh[g], xf = gsh[H_ + g], xg = gsh[2*H_ + g], xo = gsh[3*H_ + g];
            float si = 1.f / (1.f + __expf(-xi));
            float sf = 1.f / (1.f + __expf(-xf));
            float so = 1.f / (1.f + __expf(-xo));
            float eg = __expf(2.f * xg);
            float tg = 1.f - 2.f / (eg + 1.f);
            c = sf * c + si * tg;
            float ec = __expf(2.f * c);
            float th = 1.f - 2.f / (ec + 1.f);
            reinterpret_cast<_Float16*>(hsp)[g] = (_Float16)(so * th);
        }
        __syncthreads();
    }
    if (g < N_) {
        const float* worow = Wo + (size_t)g * H_;
        float o = bo[g];
        #pragma unroll
        for (int q = 0; q < 32; ++q) {
            uint4 hq = hsp4[q];
            float4 w0 = *reinterpret_cast<const float4*>(worow + q*8);
            float4 w1 = *reinterpret_cast<const float4*>(worow + q*8 + 4);
            o += w0.x * f16lo(hq.x) + w0.y * f16hi(hq.x)
               + w0.z * f16lo(hq.y) + w0.w * f16hi(hq.y)
               + w1.x * f16lo(hq.z) + w1.y * f16hi(hq.z)
               + w1.z * f16lo(hq.w) + w1.w * f16hi(hq.w);
        }
        out[(size_t)b * N_ + g] = o;
    }
}

extern "C" void kernel_launch(void* const* d_in, const int* in_sizes, int n_in,
                              void* d_out, int out_size, void* d_ws, size_t ws_size,
                              hipStream_t stream) {
    const float* x     = (const float*)d_in[0];
    const float* adj   = (const float*)d_in[1];
    const float* W     = (const float*)d_in[2];
    const float* a_src = (const float*)d_in[3];
    const float* a_dst = (const float*)d_in[4];
    const float* gat_b = (const float*)d_in[5];
    const float* W_ih  = (const float*)d_in[6];
    const float* W_hh  = (const float*)d_in[7];
    const float* b_ih  = (const float*)d_in[8];
    const float* b_hh  = (const float*)d_in[9];
    const float* Wo    = (const float*)d_in[10];
    const float* bo    = (const float*)d_in[11];
    float* out = (float*)d_out;

    // ws: seq 16MB | wih_h 16MB | G 4MB | pwv 256KB | pwl 96KB | pws 160KB
    _Float16* seq   = (_Float16*)d_ws;
    _Float16* wih_h = seq + (size_t)BT * IN_;
    float*    G     = (float*)(wih_h + (size_t)G4 * IN_);
    uint32_t* pwv   = (uint32_t*)(G + (size_t)BT * G4);
    uint32_t* pwl   = pwv + 64 * 1024;
    uint32_t* pws   = pwl + 24 * 1024;

    hipMemsetAsync(G, 0, (size_t)BT * G4 * sizeof(float), stream);
    pack_whh_kernel<<<dim3(4), dim3(256), 0, stream>>>(W_hh, pwv, pwl, pws);
    pack_wih_kernel<<<dim3(4096), dim3(256), 0, stream>>>(W_ih, wih_h);
    gat_kernel<<<dim3(BT), dim3(256), 0, stream>>>(x, adj, W, a_src, a_dst, gat_b, seq);
    gemm_kernel<<<dim3(8, 8, 8), dim3(256), 0, stream>>>(seq, wih_h, G);
    lstm_kernel<<<dim3(B_), dim3(1024), 0, stream>>>(G, pwv, pwl, pws, b_ih, b_hh, Wo, bo, out);
}

// Round 4
// 584.990 us; speedup vs baseline: 2.2789x; 1.0467x over previous
//
#include <hip/hip_runtime.h>
#include <cstdint>

constexpr int B_ = 32, T_ = 32, N_ = 256, FIN = 32, FOUT = 32, H_ = 256;
constexpr int IN_ = N_ * FOUT;   // 8192
constexpr int G4  = 4 * H_;      // 1024
constexpr int BT  = B_ * T_;     // 1024
#define NEG_SLOPE 0.2f

typedef _Float16 half8 __attribute__((ext_vector_type(8)));
typedef _Float16 h2    __attribute__((ext_vector_type(2)));
typedef float    f4    __attribute__((ext_vector_type(4)));

union U48 { uint4 u; half8 h; };

__device__ inline uint32_t pkh2(float a, float b) {
    union { uint32_t u; _Float16 h[2]; } z;
    z.h[0] = (_Float16)a; z.h[1] = (_Float16)b; return z.u;
}
__device__ inline float f16lo(uint32_t u){ union{uint32_t u; _Float16 h[2];} z; z.u=u; return (float)z.h[0]; }
__device__ inline float f16hi(uint32_t u){ union{uint32_t u; _Float16 h[2];} z; z.u=u; return (float)z.h[1]; }

__device__ inline float dot2f(uint32_t w, uint32_t h, float acc) {
    union { uint32_t u; h2 v; } a, b; a.u = w; b.u = h;
#if __has_builtin(__builtin_amdgcn_fdot2)
    return __builtin_amdgcn_fdot2(a.v, b.v, acc, false);
#else
    return acc + (float)a.v.x * (float)b.v.x + (float)a.v.y * (float)b.v.y;
#endif
}

__device__ inline void gload16(const void* g, void* l) {
    __builtin_amdgcn_global_load_lds(
        (const __attribute__((address_space(1))) void*)g,
        (__attribute__((address_space(3))) void*)l, 16, 0, 0);
}

// =====================================================================
// K1: fused GAT per (b,t). Phase 1: h = x@W per thread-node, stored
// transposed f16 hT[o][j] (pad->264). Phase 2: per-thread masked exp into
// XOR-swizzled f16 P chunks Pc[i][64], then O += Pc @ hT via MFMA.
// Wave w's A-rows == wave w's own threads' Pc rows -> NO barriers needed
// in the chunk loop (wave-internal LDS program order). 1 barrier total.
// =====================================================================
__global__ __launch_bounds__(256) void gat_kernel(
    const float* __restrict__ x, const float* __restrict__ adj,
    const float* __restrict__ W, const float* __restrict__ a_src,
    const float* __restrict__ a_dst, const float* __restrict__ gat_b,
    _Float16* __restrict__ seq)
{
    const int bt = blockIdx.x;
    const int i  = threadIdx.x;
    const int L  = i & 63, w = i >> 6;
    __shared__ float Ws[FIN * FOUT];
    __shared__ __align__(16) _Float16 hT[32 * 264];   // [o][j] pad 8
    __shared__ __align__(16) uint32_t Pc[256 * 36];   // [i][q] group-XOR-swizzled
    __shared__ float ssrc[N_];
    __shared__ float linv[N_];
    __shared__ float asv[FOUT], adv[FOUT], gbv[FOUT];

    for (int t = i; t < FIN * FOUT; t += 256) Ws[t] = W[t];
    if (i < FOUT) { asv[i] = a_src[i]; adv[i] = a_dst[i]; gbv[i] = gat_b[i]; }

    float xr[FIN];
    const float* xrow = x + ((size_t)bt * N_ + i) * FIN;
    #pragma unroll
    for (int f4i = 0; f4i < FIN / 4; ++f4i) {
        float4 v = reinterpret_cast<const float4*>(xrow)[f4i];
        xr[4*f4i] = v.x; xr[4*f4i+1] = v.y; xr[4*f4i+2] = v.z; xr[4*f4i+3] = v.w;
    }
    __syncthreads();

    float hr[FOUT];
    #pragma unroll
    for (int k4 = 0; k4 < FOUT / 4; ++k4) {
        float ax = 0.f, ay = 0.f, az = 0.f, aw = 0.f;
        #pragma unroll
        for (int f = 0; f < FIN; ++f) {
            float4 w4 = *reinterpret_cast<const float4*>(&Ws[f*FOUT + 4*k4]);
            ax += xr[f]*w4.x; ay += xr[f]*w4.y; az += xr[f]*w4.z; aw += xr[f]*w4.w;
        }
        hr[4*k4] = ax; hr[4*k4+1] = ay; hr[4*k4+2] = az; hr[4*k4+3] = aw;
    }
    float ss = 0.f, sd = 0.f;
    #pragma unroll
    for (int k = 0; k < FOUT; ++k) { ss += hr[k]*asv[k]; sd += hr[k]*adv[k]; }
    #pragma unroll
    for (int k = 0; k < FOUT; ++k) hT[k*264 + i] = (_Float16)hr[k];
    ssrc[i] = ss;
    __syncthreads();   // the ONLY barrier

    float l = 0.f;
    f4 acc[4][2] = {};                       // wave tiles: 4 i-tiles x 2 o-tiles
    const float* adjcol = adj + (size_t)bt * N_ * N_ + i;
    const int key = (i >> 3) & 3;
    const int m = L & 15, G = L >> 4;

    for (int c = 0; c < 4; ++c) {
        const int j0 = c * 64;
        #pragma unroll 8
        for (int q = 0; q < 32; ++q) {
            int ja = j0 + 2*q, jb = ja + 1;
            float a0 = adjcol[(size_t)ja * N_];
            float a1 = adjcol[(size_t)jb * N_];
            float e0 = sd + ssrc[ja]; e0 = e0 > 0.f ? e0 : NEG_SLOPE * e0;
            float e1 = sd + ssrc[jb]; e1 = e1 > 0.f ? e1 : NEG_SLOPE * e1;
            float p0 = ((a0 != 0.f) || (ja == i)) ? __expf(e0) : 0.f;
            float p1 = ((a1 != 0.f) || (jb == i)) ? __expf(e1) : 0.f;
            l += p0 + p1;
            Pc[i*36 + (((q >> 2) ^ key) << 2) + (q & 3)] = pkh2(p0, p1);
        }
        // MFMA over this chunk (K=64 -> 2 k-steps). Pc rows read belong to
        // this wave's own threads: program-order visible, no barrier.
        #pragma unroll
        for (int ks = 0; ks < 2; ++ks) {
            U48 b0, b1;
            b0.h = *reinterpret_cast<const half8*>(&hT[m*264        + j0 + ks*32 + G*8]);
            b1.h = *reinterpret_cast<const half8*>(&hT[(m+16)*264   + j0 + ks*32 + G*8]);
            #pragma unroll
            for (int it = 0; it < 4; ++it) {
                int row = w*64 + it*16 + m;
                int rkey = (row >> 3) & 3;
                U48 a;
                a.u = reinterpret_cast<const uint4*>(&Pc[row*36])[ks*4 + (G ^ rkey)];
                acc[it][0] = __builtin_amdgcn_mfma_f32_16x16x32_f16(a.h, b0.h, acc[it][0], 0, 0, 0);
                acc[it][1] = __builtin_amdgcn_mfma_f32_16x16x32_f16(a.h, b1.h, acc[it][1], 0, 0, 0);
            }
        }
    }
    linv[i] = 1.f / l;   // self-loop guarantees l > 0
    // Epilogue: rows read (w*64 + ...) are this wave's own linv entries.
    _Float16* obase = seq + (size_t)bt * IN_;
    #pragma unroll
    for (int it = 0; it < 4; ++it) {
        int ib = w*64 + it*16 + G*4;
        #pragma unroll
        for (int ot = 0; ot < 2; ++ot) {
            int o = ot*16 + m;
            float gb = gbv[o];
            #pragma unroll
            for (int r = 0; r < 4; ++r) {
                int row = ib + r;
                obase[row * FOUT + o] = (_Float16)(acc[it][ot][r] * linv[row] + gb);
            }
        }
    }
}

// =====================================================================
// K2a: W_ih f32 -> f16
// =====================================================================
__global__ __launch_bounds__(256) void pack_wih_kernel(
    const float* __restrict__ Wih, _Float16* __restrict__ out)
{
    int idx = (blockIdx.x * 256 + threadIdx.x) * 8;
    float4 v0 = *reinterpret_cast<const float4*>(Wih + idx);
    float4 v1 = *reinterpret_cast<const float4*>(Wih + idx + 4);
    half8 o;
    o[0]=(_Float16)v0.x; o[1]=(_Float16)v0.y; o[2]=(_Float16)v0.z; o[3]=(_Float16)v0.w;
    o[4]=(_Float16)v1.x; o[5]=(_Float16)v1.y; o[6]=(_Float16)v1.z; o[7]=(_Float16)v1.w;
    *reinterpret_cast<half8*>(out + idx) = o;
}

// =====================================================================
// K2b: W_hh -> f16x2 packs. p<64 pack-major (VGPR); p 64..95 -> pwl
// (LDS bulk-copy, 128KB); p 96..127 -> pws (L2 stream), uint4-grouped.
// =====================================================================
__global__ __launch_bounds__(256) void pack_whh_kernel(
    const float* __restrict__ Whh, uint32_t* __restrict__ pwv,
    uint32_t* __restrict__ pwl, uint32_t* __restrict__ pws)
{
    int g = blockIdx.x * 256 + threadIdx.x;
    const float* row = Whh + (size_t)g * H_;
    #pragma unroll
    for (int p = 0; p < 128; ++p) {
        float2 v = *reinterpret_cast<const float2*>(row + 2*p);
        uint32_t u = pkh2(v.x, v.y);
        if (p < 64) pwv[p * 1024 + g] = u;
        else if (p < 96) { int pp = p - 64; pwl[(pp >> 2) * 4096 + g * 4 + (pp & 3)] = u; }
        else             { int pp = p - 96; pws[(pp >> 2) * 4096 + g * 4 + (pp & 3)] = u; }
    }
}

// =====================================================================
// K3: f16 MFMA GEMM  G[m=bt][n] += A[m][k] * B[n][k]
// 128x128 tile, BK=32, split-K=8 (atomicAdd, G zeroed).
// =====================================================================
__global__ __launch_bounds__(256, 4) void gemm_kernel(
    const _Float16* __restrict__ A, const _Float16* __restrict__ Bh,
    float* __restrict__ G)
{
    __shared__ __align__(16) _Float16 As[128 * 32];
    __shared__ __align__(16) _Float16 Bs[128 * 32];
    const int t = threadIdx.x;
    const int L = t & 63, w = t >> 6;
    const int wm = w & 1, wn = w >> 1;
    const int m0 = blockIdx.y * 128, n0 = blockIdx.x * 128;
    const int kz = blockIdx.z * 1024;

    f4 acc[4][4] = {};
    const int q0 = t, q1 = t + 256;
    const int row0 = q0 >> 2, kc0 = q0 & 3;
    const int row1 = q1 >> 2, kc1 = q1 & 3;
    const int la = (L & 15) * 32 + (L >> 4) * 8;

    const _Float16* A0 = A + (size_t)(m0 + row0) * IN_ + kz + kc0 * 8;
    const _Float16* A1 = A + (size_t)(m0 + row1) * IN_ + kz + kc1 * 8;
    const _Float16* B0 = Bh + (size_t)(n0 + row0) * IN_ + kz + kc0 * 8;
    const _Float16* B1 = Bh + (size_t)(n0 + row1) * IN_ + kz + kc1 * 8;
    for (int kb = 0; kb < 1024; kb += 32) {
        __syncthreads();
        gload16(A0 + kb, &As[q0 * 8]);
        gload16(A1 + kb, &As[q1 * 8]);
        gload16(B0 + kb, &Bs[q0 * 8]);
        gload16(B1 + kb, &Bs[q1 * 8]);
        __syncthreads();
        half8 af[4], bf[4];
        #pragma unroll
        for (int mi = 0; mi < 4; ++mi)
            af[mi] = *reinterpret_cast<const half8*>(&As[(wm*64 + mi*16) * 32 + la]);
        #pragma unroll
        for (int ni = 0; ni < 4; ++ni)
            bf[ni] = *reinterpret_cast<const half8*>(&Bs[(wn*64 + ni*16) * 32 + la]);
        #pragma unroll
        for (int mi = 0; mi < 4; ++mi)
            #pragma unroll
            for (int ni = 0; ni < 4; ++ni)
                acc[mi][ni] = __builtin_amdgcn_mfma_f32_16x16x32_f16(
                    af[mi], bf[ni], acc[mi][ni], 0, 0, 0);
    }
    const int cn = n0 + wn * 64 + (L & 15);
    const int rm = m0 + wm * 64 + (L >> 4) * 4;
    #pragma unroll
    for (int mi = 0; mi < 4; ++mi)
        #pragma unroll
        for (int ni = 0; ni < 4; ++ni)
            #pragma unroll
            for (int r = 0; r < 4; ++r)
                atomicAdd(&G[(size_t)(rm + mi*16 + r) * G4 + cn + ni*16], acc[mi][ni][r]);
}

// =====================================================================
// K4: LSTM recurrence + output linear. Block per b, thread = gate row.
// W_hh row (128 f16x2 packs): 64 VGPR + 32 LDS (128KB) + 32 streamed (L2).
// =====================================================================
__global__ __launch_bounds__(1024) void lstm_kernel(
    const float* __restrict__ G, const uint32_t* __restrict__ pwv,
    const uint32_t* __restrict__ pwl, const uint32_t* __restrict__ pws,
    const float* __restrict__ b_ih, const float* __restrict__ b_hh,
    const float* __restrict__ Wo, const float* __restrict__ bo,
    float* __restrict__ out)
{
    const int b = blockIdx.x;
    const int g = threadIdx.x;
    __shared__ __align__(16) uint32_t hsp[128];      // h as f16x2
    __shared__ float gsh[G4];
    __shared__ __align__(16) uint32_t wl[8 * 4096];  // 32 packs x 1024 = 128KB

    uint32_t wv[64];
    #pragma unroll
    for (int p = 0; p < 64; ++p) wv[p] = pwv[p * 1024 + g];
    {
        const uint4* s = reinterpret_cast<const uint4*>(pwl);
        uint4* d = reinterpret_cast<uint4*>(wl);
        #pragma unroll
        for (int r = 0; r < 8; ++r) d[r * 1024 + g] = s[r * 1024 + g];
    }
    if (g < 128) hsp[g] = 0u;
    float c = 0.f;
    const float bias = b_ih[g] + b_hh[g];
    const float* Gb = G + (size_t)b * T_ * G4 + g;
    const uint4* pws4 = reinterpret_cast<const uint4*>(pws);
    const uint4* wl4  = reinterpret_cast<const uint4*>(wl);
    const uint4* hsp4 = reinterpret_cast<const uint4*>(hsp);
    float gnext = Gb[0];
    __syncthreads();

    for (int t = 0; t < T_; ++t) {
        float acc = bias + gnext;
        if (t + 1 < T_) gnext = Gb[(size_t)(t + 1) * G4];
        #pragma unroll
        for (int q = 0; q < 32; ++q) {
            uint4 h4 = hsp4[q];
            uint4 w4;
            if (q < 16) {
                w4.x = wv[4*q]; w4.y = wv[4*q+1]; w4.z = wv[4*q+2]; w4.w = wv[4*q+3];
            } else if (q < 24) {
                w4 = wl4[(q - 16) * 1024 + g];
            } else {
                w4 = pws4[(q - 24) * 1024 + g];
            }
            acc = dot2f(w4.x, h4.x, acc);
            acc = dot2f(w4.y, h4.y, acc);
            acc = dot2f(w4.z, h4.z, acc);
            acc = dot2f(w4.w, h4.w, acc);
        }
        gsh[g] = acc;
        __syncthreads();
        if (g < H_) {
            float xi = gsh[g], xf = gsh[H_ + g], xg = gsh[2*H_ + g], xo = gsh[3*H_ + g];
            float si = 1.f / (1.f + __expf(-xi));
            float sf = 1.f / (1.f + __expf(-xf));
            float so = 1.f / (1.f + __expf(-xo));
            float eg = __expf(2.f * xg);
            float tg = 1.f - 2.f / (eg + 1.f);
            c = sf * c + si * tg;
            float ec = __expf(2.f * c);
            float th = 1.f - 2.f / (ec + 1.f);
            reinterpret_cast<_Float16*>(hsp)[g] = (_Float16)(so * th);
        }
        __syncthreads();
    }
    if (g < N_) {
        const float* worow = Wo + (size_t)g * H_;
        float o = bo[g];
        #pragma unroll
        for (int q = 0; q < 32; ++q) {
            uint4 hq = hsp4[q];
            float4 w0 = *reinterpret_cast<const float4*>(worow + q*8);
            float4 w1 = *reinterpret_cast<const float4*>(worow + q*8 + 4);
            o += w0.x * f16lo(hq.x) + w0.y * f16hi(hq.x)
               + w0.z * f16lo(hq.y) + w0.w * f16hi(hq.y)
               + w1.x * f16lo(hq.z) + w1.y * f16hi(hq.z)
               + w1.z * f16lo(hq.w) + w1.w * f16hi(hq.w);
        }
        out[(size_t)b * N_ + g] = o;
    }
}

extern "C" void kernel_launch(void* const* d_in, const int* in_sizes, int n_in,
                              void* d_out, int out_size, void* d_ws, size_t ws_size,
                              hipStream_t stream) {
    const float* x     = (const float*)d_in[0];
    const float* adj   = (const float*)d_in[1];
    const float* W     = (const float*)d_in[2];
    const float* a_src = (const float*)d_in[3];
    const float* a_dst = (const float*)d_in[4];
    const float* gat_b = (const float*)d_in[5];
    const float* W_ih  = (const float*)d_in[6];
    const float* W_hh  = (const float*)d_in[7];
    const float* b_ih  = (const float*)d_in[8];
    const float* b_hh  = (const float*)d_in[9];
    const float* Wo    = (const float*)d_in[10];
    const float* bo    = (const float*)d_in[11];
    float* out = (float*)d_out;

    // ws: seq 16MB | wih_h 16MB | G 4MB | pwv 256KB | pwl 128KB | pws 128KB
    _Float16* seq   = (_Float16*)d_ws;
    _Float16* wih_h = seq + (size_t)BT * IN_;
    float*    G     = (float*)(wih_h + (size_t)G4 * IN_);
    uint32_t* pwv   = (uint32_t*)(G + (size_t)BT * G4);
    uint32_t* pwl   = pwv + 64 * 1024;
    uint32_t* pws   = pwl + 32 * 1024;

    hipMemsetAsync(G, 0, (size_t)BT * G4 * sizeof(float), stream);
    pack_whh_kernel<<<dim3(4), dim3(256), 0, stream>>>(W_hh, pwv, pwl, pws);
    pack_wih_kernel<<<dim3(4096), dim3(256), 0, stream>>>(W_ih, wih_h);
    gat_kernel<<<dim3(BT), dim3(256), 0, stream>>>(x, adj, W, a_src, a_dst, gat_b, seq);
    gemm_kernel<<<dim3(8, 8, 8), dim3(256), 0, stream>>>(seq, wih_h, G);
    lstm_kernel<<<dim3(B_), dim3(1024), 0, stream>>>(G, pwv, pwl, pws, b_ih, b_hh, Wo, bo, out);
}

// Round 5
// 569.758 us; speedup vs baseline: 2.3398x; 1.0267x over previous
//
#include <hip/hip_runtime.h>
#include <cstdint>

constexpr int B_ = 32, T_ = 32, N_ = 256, FIN = 32, FOUT = 32, H_ = 256;
constexpr int IN_ = N_ * FOUT;   // 8192
constexpr int G4  = 4 * H_;      // 1024
constexpr int BT  = B_ * T_;     // 1024
constexpr int KZ  = 8;           // split-K partials
#define NEG_SLOPE 0.2f

typedef _Float16 half8 __attribute__((ext_vector_type(8)));
typedef _Float16 h2    __attribute__((ext_vector_type(2)));
typedef float    f4    __attribute__((ext_vector_type(4)));

union U48 { uint4 u; half8 h; };

__device__ inline uint32_t pkh2(float a, float b) {
    union { uint32_t u; _Float16 h[2]; } z;
    z.h[0] = (_Float16)a; z.h[1] = (_Float16)b; return z.u;
}
__device__ inline float f16lo(uint32_t u){ union{uint32_t u; _Float16 h[2];} z; z.u=u; return (float)z.h[0]; }
__device__ inline float f16hi(uint32_t u){ union{uint32_t u; _Float16 h[2];} z; z.u=u; return (float)z.h[1]; }

__device__ inline float dot2f(uint32_t w, uint32_t h, float acc) {
    union { uint32_t u; h2 v; } a, b; a.u = w; b.u = h;
#if __has_builtin(__builtin_amdgcn_fdot2)
    return __builtin_amdgcn_fdot2(a.v, b.v, acc, false);
#else
    return acc + (float)a.v.x * (float)b.v.x + (float)a.v.y * (float)b.v.y;
#endif
}

__device__ inline void gload16(const void* g, void* l) {
    __builtin_amdgcn_global_load_lds(
        (const __attribute__((address_space(1))) void*)g,
        (__attribute__((address_space(3))) void*)l, 16, 0, 0);
}

// =====================================================================
// K1: fused GAT per (b,t). Phase 1: h = x@W per thread-node, stored
// transposed f16 hT[o][j] (pad->264). Phase 2: per-thread masked exp into
// XOR-swizzled f16 P chunks Pc[i][64], then O += Pc @ hT via MFMA.
// Wave w's A-rows == wave w's own threads' Pc rows -> no barriers in the
// chunk loop (wave-internal LDS program order). 1 barrier total.
// =====================================================================
__global__ __launch_bounds__(256) void gat_kernel(
    const float* __restrict__ x, const float* __restrict__ adj,
    const float* __restrict__ W, const float* __restrict__ a_src,
    const float* __restrict__ a_dst, const float* __restrict__ gat_b,
    _Float16* __restrict__ seq)
{
    const int bt = blockIdx.x;
    const int i  = threadIdx.x;
    const int L  = i & 63, w = i >> 6;
    __shared__ float Ws[FIN * FOUT];
    __shared__ __align__(16) _Float16 hT[32 * 264];   // [o][j] pad 8
    __shared__ __align__(16) uint32_t Pc[256 * 36];   // [i][q] group-XOR-swizzled
    __shared__ float ssrc[N_];
    __shared__ float linv[N_];
    __shared__ float asv[FOUT], adv[FOUT], gbv[FOUT];

    for (int t = i; t < FIN * FOUT; t += 256) Ws[t] = W[t];
    if (i < FOUT) { asv[i] = a_src[i]; adv[i] = a_dst[i]; gbv[i] = gat_b[i]; }

    float xr[FIN];
    const float* xrow = x + ((size_t)bt * N_ + i) * FIN;
    #pragma unroll
    for (int f4i = 0; f4i < FIN / 4; ++f4i) {
        float4 v = reinterpret_cast<const float4*>(xrow)[f4i];
        xr[4*f4i] = v.x; xr[4*f4i+1] = v.y; xr[4*f4i+2] = v.z; xr[4*f4i+3] = v.w;
    }
    __syncthreads();

    float hr[FOUT];
    #pragma unroll
    for (int k4 = 0; k4 < FOUT / 4; ++k4) {
        float ax = 0.f, ay = 0.f, az = 0.f, aw = 0.f;
        #pragma unroll
        for (int f = 0; f < FIN; ++f) {
            float4 w4 = *reinterpret_cast<const float4*>(&Ws[f*FOUT + 4*k4]);
            ax += xr[f]*w4.x; ay += xr[f]*w4.y; az += xr[f]*w4.z; aw += xr[f]*w4.w;
        }
        hr[4*k4] = ax; hr[4*k4+1] = ay; hr[4*k4+2] = az; hr[4*k4+3] = aw;
    }
    float ss = 0.f, sd = 0.f;
    #pragma unroll
    for (int k = 0; k < FOUT; ++k) { ss += hr[k]*asv[k]; sd += hr[k]*adv[k]; }
    #pragma unroll
    for (int k = 0; k < FOUT; ++k) hT[k*264 + i] = (_Float16)hr[k];
    ssrc[i] = ss;
    __syncthreads();   // the ONLY barrier

    float l = 0.f;
    f4 acc[4][2] = {};                       // wave tiles: 4 i-tiles x 2 o-tiles
    const float* adjcol = adj + (size_t)bt * N_ * N_ + i;
    const int key = (i >> 3) & 3;
    const int m = L & 15, G = L >> 4;

    for (int c = 0; c < 4; ++c) {
        const int j0 = c * 64;
        #pragma unroll 8
        for (int q = 0; q < 32; ++q) {
            int ja = j0 + 2*q, jb = ja + 1;
            float a0 = adjcol[(size_t)ja * N_];
            float a1 = adjcol[(size_t)jb * N_];
            float e0 = sd + ssrc[ja]; e0 = e0 > 0.f ? e0 : NEG_SLOPE * e0;
            float e1 = sd + ssrc[jb]; e1 = e1 > 0.f ? e1 : NEG_SLOPE * e1;
            float p0 = ((a0 != 0.f) || (ja == i)) ? __expf(e0) : 0.f;
            float p1 = ((a1 != 0.f) || (jb == i)) ? __expf(e1) : 0.f;
            l += p0 + p1;
            Pc[i*36 + (((q >> 2) ^ key) << 2) + (q & 3)] = pkh2(p0, p1);
        }
        #pragma unroll
        for (int ks = 0; ks < 2; ++ks) {
            U48 b0, b1;
            b0.h = *reinterpret_cast<const half8*>(&hT[m*264      + j0 + ks*32 + G*8]);
            b1.h = *reinterpret_cast<const half8*>(&hT[(m+16)*264 + j0 + ks*32 + G*8]);
            #pragma unroll
            for (int it = 0; it < 4; ++it) {
                int row = w*64 + it*16 + m;
                int rkey = (row >> 3) & 3;
                U48 a;
                a.u = reinterpret_cast<const uint4*>(&Pc[row*36])[ks*4 + (G ^ rkey)];
                acc[it][0] = __builtin_amdgcn_mfma_f32_16x16x32_f16(a.h, b0.h, acc[it][0], 0, 0, 0);
                acc[it][1] = __builtin_amdgcn_mfma_f32_16x16x32_f16(a.h, b1.h, acc[it][1], 0, 0, 0);
            }
        }
    }
    linv[i] = 1.f / l;   // self-loop guarantees l > 0
    _Float16* obase = seq + (size_t)bt * IN_;
    #pragma unroll
    for (int it = 0; it < 4; ++it) {
        int ib = w*64 + it*16 + G*4;
        #pragma unroll
        for (int ot = 0; ot < 2; ++ot) {
            int o = ot*16 + m;
            float gb = gbv[o];
            #pragma unroll
            for (int r = 0; r < 4; ++r) {
                int row = ib + r;
                obase[row * FOUT + o] = (_Float16)(acc[it][ot][r] * linv[row] + gb);
            }
        }
    }
}

// =====================================================================
// K2: merged pack. Blocks 0..4095: W_ih f32->f16 (8 elems/thread).
// Blocks 4096..4099: W_hh -> f16x2 packs (p<64 VGPR-major pwv;
// 64..95 -> pwl uint4-grouped LDS copy; 96..127 -> pws L2 stream).
// =====================================================================
__global__ __launch_bounds__(256) void pack_kernel(
    const float* __restrict__ Wih, const float* __restrict__ Whh,
    _Float16* __restrict__ wih_h, uint32_t* __restrict__ pwv,
    uint32_t* __restrict__ pwl, uint32_t* __restrict__ pws)
{
    if (blockIdx.x < 4096) {
        int idx = (blockIdx.x * 256 + threadIdx.x) * 8;
        float4 v0 = *reinterpret_cast<const float4*>(Wih + idx);
        float4 v1 = *reinterpret_cast<const float4*>(Wih + idx + 4);
        half8 o;
        o[0]=(_Float16)v0.x; o[1]=(_Float16)v0.y; o[2]=(_Float16)v0.z; o[3]=(_Float16)v0.w;
        o[4]=(_Float16)v1.x; o[5]=(_Float16)v1.y; o[6]=(_Float16)v1.z; o[7]=(_Float16)v1.w;
        *reinterpret_cast<half8*>(wih_h + idx) = o;
    } else {
        int g = (blockIdx.x - 4096) * 256 + threadIdx.x;
        const float* row = Whh + (size_t)g * H_;
        #pragma unroll
        for (int p = 0; p < 128; ++p) {
            float2 v = *reinterpret_cast<const float2*>(row + 2*p);
            uint32_t u = pkh2(v.x, v.y);
            if (p < 64) pwv[p * 1024 + g] = u;
            else if (p < 96) { int pp = p - 64; pwl[(pp >> 2) * 4096 + g * 4 + (pp & 3)] = u; }
            else             { int pp = p - 96; pws[(pp >> 2) * 4096 + g * 4 + (pp & 3)] = u; }
        }
    }
}

// =====================================================================
// K3: f16 MFMA GEMM  Gp[z][m=bt][n] = A[m][k] * B[n][k] over k-slice z.
// 128x128 tile, BK=32, split-K=8 into SEPARATE partials: plain stores,
// no atomics, no pre-zero. LSTM sums the 8 partials.
// =====================================================================
__global__ __launch_bounds__(256, 4) void gemm_kernel(
    const _Float16* __restrict__ A, const _Float16* __restrict__ Bh,
    float* __restrict__ Gp)
{
    __shared__ __align__(16) _Float16 As[128 * 32];
    __shared__ __align__(16) _Float16 Bs[128 * 32];
    const int t = threadIdx.x;
    const int L = t & 63, w = t >> 6;
    const int wm = w & 1, wn = w >> 1;
    const int m0 = blockIdx.y * 128, n0 = blockIdx.x * 128;
    const int kz = blockIdx.z * 1024;

    f4 acc[4][4] = {};
    const int q0 = t, q1 = t + 256;
    const int row0 = q0 >> 2, kc0 = q0 & 3;
    const int row1 = q1 >> 2, kc1 = q1 & 3;
    const int la = (L & 15) * 32 + (L >> 4) * 8;

    const _Float16* A0 = A + (size_t)(m0 + row0) * IN_ + kz + kc0 * 8;
    const _Float16* A1 = A + (size_t)(m0 + row1) * IN_ + kz + kc1 * 8;
    const _Float16* B0 = Bh + (size_t)(n0 + row0) * IN_ + kz + kc0 * 8;
    const _Float16* B1 = Bh + (size_t)(n0 + row1) * IN_ + kz + kc1 * 8;
    for (int kb = 0; kb < 1024; kb += 32) {
        __syncthreads();
        gload16(A0 + kb, &As[q0 * 8]);
        gload16(A1 + kb, &As[q1 * 8]);
        gload16(B0 + kb, &Bs[q0 * 8]);
        gload16(B1 + kb, &Bs[q1 * 8]);
        __syncthreads();
        half8 af[4], bf[4];
        #pragma unroll
        for (int mi = 0; mi < 4; ++mi)
            af[mi] = *reinterpret_cast<const half8*>(&As[(wm*64 + mi*16) * 32 + la]);
        #pragma unroll
        for (int ni = 0; ni < 4; ++ni)
            bf[ni] = *reinterpret_cast<const half8*>(&Bs[(wn*64 + ni*16) * 32 + la]);
        #pragma unroll
        for (int mi = 0; mi < 4; ++mi)
            #pragma unroll
            for (int ni = 0; ni < 4; ++ni)
                acc[mi][ni] = __builtin_amdgcn_mfma_f32_16x16x32_f16(
                    af[mi], bf[ni], acc[mi][ni], 0, 0, 0);
    }
    float* Gz = Gp + (size_t)blockIdx.z * BT * G4;
    const int cn = n0 + wn * 64 + (L & 15);
    const int rm = m0 + wm * 64 + (L >> 4) * 4;
    #pragma unroll
    for (int mi = 0; mi < 4; ++mi)
        #pragma unroll
        for (int ni = 0; ni < 4; ++ni)
            #pragma unroll
            for (int r = 0; r < 4; ++r)
                Gz[(size_t)(rm + mi*16 + r) * G4 + cn + ni*16] = acc[mi][ni][r];
}

// =====================================================================
// K4: LSTM recurrence + output linear. Block per b, thread = gate row.
// Gate preactivation = bias + sum of 8 split-K partials (prefetched one
// timestep ahead, overlapped with the dot2 chain).
// W_hh row (128 f16x2 packs): 64 VGPR + 32 LDS (128KB) + 32 streamed (L2).
// =====================================================================
__global__ __launch_bounds__(1024) void lstm_kernel(
    const float* __restrict__ Gp, const uint32_t* __restrict__ pwv,
    const uint32_t* __restrict__ pwl, const uint32_t* __restrict__ pws,
    const float* __restrict__ b_ih, const float* __restrict__ b_hh,
    const float* __restrict__ Wo, const float* __restrict__ bo,
    float* __restrict__ out)
{
    const int b = blockIdx.x;
    const int g = threadIdx.x;
    __shared__ __align__(16) uint32_t hsp[128];      // h as f16x2
    __shared__ float gsh[G4];
    __shared__ __align__(16) uint32_t wl[8 * 4096];  // 32 packs x 1024 = 128KB

    uint32_t wv[64];
    #pragma unroll
    for (int p = 0; p < 64; ++p) wv[p] = pwv[p * 1024 + g];
    {
        const uint4* s = reinterpret_cast<const uint4*>(pwl);
        uint4* d = reinterpret_cast<uint4*>(wl);
        #pragma unroll
        for (int r = 0; r < 8; ++r) d[r * 1024 + g] = s[r * 1024 + g];
    }
    if (g < 128) hsp[g] = 0u;
    float c = 0.f;
    const float bias = b_ih[g] + b_hh[g];
    const size_t zs = (size_t)BT * G4;
    const float* Gb = Gp + (size_t)b * T_ * G4 + g;
    const uint4* pws4 = reinterpret_cast<const uint4*>(pws);
    const uint4* wl4  = reinterpret_cast<const uint4*>(wl);
    const uint4* hsp4 = reinterpret_cast<const uint4*>(hsp);

    float gcur = 0.f;
    #pragma unroll
    for (int z = 0; z < KZ; ++z) gcur += Gb[z * zs];
    __syncthreads();

    for (int t = 0; t < T_; ++t) {
        float acc = bias + gcur;
        float pf[KZ];
        const int tn = (t + 1 < T_) ? t + 1 : t;   // harmless dup on last iter
        #pragma unroll
        for (int z = 0; z < KZ; ++z) pf[z] = Gb[(size_t)tn * G4 + z * zs];
        #pragma unroll
        for (int q = 0; q < 32; ++q) {
            uint4 h4 = hsp4[q];
            uint4 w4;
            if (q < 16) {
                w4.x = wv[4*q]; w4.y = wv[4*q+1]; w4.z = wv[4*q+2]; w4.w = wv[4*q+3];
            } else if (q < 24) {
                w4 = wl4[(q - 16) * 1024 + g];
            } else {
                w4 = pws4[(q - 24) * 1024 + g];
            }
            acc = dot2f(w4.x, h4.x, acc);
            acc = dot2f(w4.y, h4.y, acc);
            acc = dot2f(w4.z, h4.z, acc);
            acc = dot2f(w4.w, h4.w, acc);
        }
        gcur = ((pf[0]+pf[1]) + (pf[2]+pf[3])) + ((pf[4]+pf[5]) + (pf[6]+pf[7]));
        gsh[g] = acc;
        __syncthreads();
        if (g < H_) {
            float xi = gsh[g], xf = gsh[H_ + g], xg = gsh[2*H_ + g], xo = gsh[3*H_ + g];
            float si = 1.f / (1.f + __expf(-xi));
            float sf = 1.f / (1.f + __expf(-xf));
            float so = 1.f / (1.f + __expf(-xo));
            float eg = __expf(2.f * xg);
            float tg = 1.f - 2.f / (eg + 1.f);
            c = sf * c + si * tg;
            float ec = __expf(2.f * c);
            float th = 1.f - 2.f / (ec + 1.f);
            reinterpret_cast<_Float16*>(hsp)[g] = (_Float16)(so * th);
        }
        __syncthreads();
    }
    if (g < N_) {
        const float* worow = Wo + (size_t)g * H_;
        float o = bo[g];
        #pragma unroll
        for (int q = 0; q < 32; ++q) {
            uint4 hq = hsp4[q];
            float4 w0 = *reinterpret_cast<const float4*>(worow + q*8);
            float4 w1 = *reinterpret_cast<const float4*>(worow + q*8 + 4);
            o += w0.x * f16lo(hq.x) + w0.y * f16hi(hq.x)
               + w0.z * f16lo(hq.y) + w0.w * f16hi(hq.y)
               + w1.x * f16lo(hq.z) + w1.y * f16hi(hq.z)
               + w1.z * f16lo(hq.w) + w1.w * f16hi(hq.w);
        }
        out[(size_t)b * N_ + g] = o;
    }
}

extern "C" void kernel_launch(void* const* d_in, const int* in_sizes, int n_in,
                              void* d_out, int out_size, void* d_ws, size_t ws_size,
                              hipStream_t stream) {
    const float* x     = (const float*)d_in[0];
    const float* adj   = (const float*)d_in[1];
    const float* W     = (const float*)d_in[2];
    const float* a_src = (const float*)d_in[3];
    const float* a_dst = (const float*)d_in[4];
    const float* gat_b = (const float*)d_in[5];
    const float* W_ih  = (const float*)d_in[6];
    const float* W_hh  = (const float*)d_in[7];
    const float* b_ih  = (const float*)d_in[8];
    const float* b_hh  = (const float*)d_in[9];
    const float* Wo    = (const float*)d_in[10];
    const float* bo    = (const float*)d_in[11];
    float* out = (float*)d_out;

    // ws: seq 16MB | wih_h 16MB | Gp 32MB (8 partials) | pwv 256KB | pwl 128KB | pws 128KB
    _Float16* seq   = (_Float16*)d_ws;
    _Float16* wih_h = seq + (size_t)BT * IN_;
    float*    Gp    = (float*)(wih_h + (size_t)G4 * IN_);
    uint32_t* pwv   = (uint32_t*)(Gp + (size_t)KZ * BT * G4);
    uint32_t* pwl   = pwv + 64 * 1024;
    uint32_t* pws   = pwl + 32 * 1024;

    pack_kernel<<<dim3(4100), dim3(256), 0, stream>>>(W_ih, W_hh, wih_h, pwv, pwl, pws);
    gat_kernel<<<dim3(BT), dim3(256), 0, stream>>>(x, adj, W, a_src, a_dst, gat_b, seq);
    gemm_kernel<<<dim3(8, 8, KZ), dim3(256), 0, stream>>>(seq, wih_h, Gp);
    lstm_kernel<<<dim3(B_), dim3(1024), 0, stream>>>(Gp, pwv, pwl, pws, b_ih, b_hh, Wo, bo, out);
}

// Round 6
// 553.843 us; speedup vs baseline: 2.4071x; 1.0287x over previous
//
#include <hip/hip_runtime.h>
#include <cstdint>

constexpr int B_ = 32, T_ = 32, N_ = 256, FIN = 32, FOUT = 32, H_ = 256;
constexpr int IN_ = N_ * FOUT;   // 8192
constexpr int G4  = 4 * H_;      // 1024
constexpr int BT  = B_ * T_;     // 1024
constexpr int KZ  = 8;           // split-K partials
constexpr int NPACK = 4100;      // pack blocks prepended to gat grid
#define NEG_SLOPE 0.2f

typedef _Float16 half8 __attribute__((ext_vector_type(8)));
typedef _Float16 h2    __attribute__((ext_vector_type(2)));
typedef float    f4    __attribute__((ext_vector_type(4)));

union U48 { uint4 u; half8 h; };

__device__ inline uint32_t pkh2(float a, float b) {
    union { uint32_t u; _Float16 h[2]; } z;
    z.h[0] = (_Float16)a; z.h[1] = (_Float16)b; return z.u;
}
__device__ inline float f16lo(uint32_t u){ union{uint32_t u; _Float16 h[2];} z; z.u=u; return (float)z.h[0]; }
__device__ inline float f16hi(uint32_t u){ union{uint32_t u; _Float16 h[2];} z; z.u=u; return (float)z.h[1]; }

__device__ inline float dot2f(uint32_t w, uint32_t h, float acc) {
    union { uint32_t u; h2 v; } a, b; a.u = w; b.u = h;
#if __has_builtin(__builtin_amdgcn_fdot2)
    return __builtin_amdgcn_fdot2(a.v, b.v, acc, false);
#else
    return acc + (float)a.v.x * (float)b.v.x + (float)a.v.y * (float)b.v.y;
#endif
}

__device__ inline void gload16(const void* g, void* l) {
    __builtin_amdgcn_global_load_lds(
        (const __attribute__((address_space(1))) void*)g,
        (__attribute__((address_space(3))) void*)l, 16, 0, 0);
}

// =====================================================================
// K1: merged pack + fused GAT.
// Blocks 0..4095: W_ih f32->f16. Blocks 4096..4099: W_hh -> f16x2 packs.
// Blocks 4100..5123: GAT for bt = blockIdx-4100 (pack co-runs under the
// adj-HBM-bound GAT, hiding its ~10us of memory work).
// GAT: h=x@W -> hT[o][j] f16 (pad 264); per-thread masked exp into
// XOR-swizzled K=32 P-chunks Pc[i][16 packs, pad 20] (43KB LDS total ->
// 3 blocks/CU); O += Pc @ hT via MFMA. Wave's A-rows are its own
// threads' rows -> no barrier in the chunk loop; 1 barrier total.
// =====================================================================
__global__ __launch_bounds__(256) void gat_pack_kernel(
    const float* __restrict__ x, const float* __restrict__ adj,
    const float* __restrict__ W, const float* __restrict__ a_src,
    const float* __restrict__ a_dst, const float* __restrict__ gat_b,
    _Float16* __restrict__ seq,
    const float* __restrict__ Wih, const float* __restrict__ Whh,
    _Float16* __restrict__ wih_h, uint32_t* __restrict__ pwv,
    uint32_t* __restrict__ pwl, uint32_t* __restrict__ pws)
{
    if (blockIdx.x < NPACK) {
        if (blockIdx.x < 4096) {
            int idx = (blockIdx.x * 256 + threadIdx.x) * 8;
            float4 v0 = *reinterpret_cast<const float4*>(Wih + idx);
            float4 v1 = *reinterpret_cast<const float4*>(Wih + idx + 4);
            half8 o;
            o[0]=(_Float16)v0.x; o[1]=(_Float16)v0.y; o[2]=(_Float16)v0.z; o[3]=(_Float16)v0.w;
            o[4]=(_Float16)v1.x; o[5]=(_Float16)v1.y; o[6]=(_Float16)v1.z; o[7]=(_Float16)v1.w;
            *reinterpret_cast<half8*>(wih_h + idx) = o;
        } else {
            int g = (blockIdx.x - 4096) * 256 + threadIdx.x;
            const float* row = Whh + (size_t)g * H_;
            #pragma unroll
            for (int p = 0; p < 128; ++p) {
                float2 v = *reinterpret_cast<const float2*>(row + 2*p);
                uint32_t u = pkh2(v.x, v.y);
                if (p < 64) pwv[p * 1024 + g] = u;
                else if (p < 96) { int pp = p - 64; pwl[(pp >> 2) * 4096 + g * 4 + (pp & 3)] = u; }
                else             { int pp = p - 96; pws[(pp >> 2) * 4096 + g * 4 + (pp & 3)] = u; }
            }
        }
        return;
    }

    const int bt = blockIdx.x - NPACK;
    const int i  = threadIdx.x;
    const int L  = i & 63, w = i >> 6;
    __shared__ float Ws[FIN * FOUT];
    __shared__ __align__(16) _Float16 hT[32 * 264];   // [o][j] pad 8
    __shared__ __align__(16) uint32_t Pc[256 * 20];   // [i][q] K=32 chunk, swizzled
    __shared__ float ssrc[N_];
    __shared__ float linv[N_];
    __shared__ float asv[FOUT], adv[FOUT], gbv[FOUT];

    for (int t = i; t < FIN * FOUT; t += 256) Ws[t] = W[t];
    if (i < FOUT) { asv[i] = a_src[i]; adv[i] = a_dst[i]; gbv[i] = gat_b[i]; }

    float xr[FIN];
    const float* xrow = x + ((size_t)bt * N_ + i) * FIN;
    #pragma unroll
    for (int f4i = 0; f4i < FIN / 4; ++f4i) {
        float4 v = reinterpret_cast<const float4*>(xrow)[f4i];
        xr[4*f4i] = v.x; xr[4*f4i+1] = v.y; xr[4*f4i+2] = v.z; xr[4*f4i+3] = v.w;
    }
    __syncthreads();

    float hr[FOUT];
    #pragma unroll
    for (int k4 = 0; k4 < FOUT / 4; ++k4) {
        float ax = 0.f, ay = 0.f, az = 0.f, aw = 0.f;
        #pragma unroll
        for (int f = 0; f < FIN; ++f) {
            float4 w4 = *reinterpret_cast<const float4*>(&Ws[f*FOUT + 4*k4]);
            ax += xr[f]*w4.x; ay += xr[f]*w4.y; az += xr[f]*w4.z; aw += xr[f]*w4.w;
        }
        hr[4*k4] = ax; hr[4*k4+1] = ay; hr[4*k4+2] = az; hr[4*k4+3] = aw;
    }
    float ss = 0.f, sd = 0.f;
    #pragma unroll
    for (int k = 0; k < FOUT; ++k) { ss += hr[k]*asv[k]; sd += hr[k]*adv[k]; }
    #pragma unroll
    for (int k = 0; k < FOUT; ++k) hT[k*264 + i] = (_Float16)hr[k];
    ssrc[i] = ss;
    __syncthreads();   // the ONLY barrier

    float l = 0.f;
    f4 acc[4][2] = {};                       // wave tiles: 4 i-tiles x 2 o-tiles
    const float* adjcol = adj + (size_t)bt * N_ * N_ + i;
    const int key = (i >> 3) & 3;
    const int m = L & 15, G = L >> 4;

    for (int c = 0; c < 8; ++c) {
        const int j0 = c * 32;
        #pragma unroll
        for (int q = 0; q < 16; ++q) {
            int ja = j0 + 2*q, jb = ja + 1;
            float a0 = adjcol[(size_t)ja * N_];
            float a1 = adjcol[(size_t)jb * N_];
            float e0 = sd + ssrc[ja]; e0 = e0 > 0.f ? e0 : NEG_SLOPE * e0;
            float e1 = sd + ssrc[jb]; e1 = e1 > 0.f ? e1 : NEG_SLOPE * e1;
            float p0 = ((a0 != 0.f) || (ja == i)) ? __expf(e0) : 0.f;
            float p1 = ((a1 != 0.f) || (jb == i)) ? __expf(e1) : 0.f;
            l += p0 + p1;
            Pc[i*20 + (((q >> 2) ^ key) << 2) + (q & 3)] = pkh2(p0, p1);
        }
        U48 b0, b1;
        b0.h = *reinterpret_cast<const half8*>(&hT[m*264      + j0 + G*8]);
        b1.h = *reinterpret_cast<const half8*>(&hT[(m+16)*264 + j0 + G*8]);
        #pragma unroll
        for (int it = 0; it < 4; ++it) {
            int row = w*64 + it*16 + m;
            int rkey = (row >> 3) & 3;
            U48 a;
            a.u = reinterpret_cast<const uint4*>(&Pc[row*20])[G ^ rkey];
            acc[it][0] = __builtin_amdgcn_mfma_f32_16x16x32_f16(a.h, b0.h, acc[it][0], 0, 0, 0);
            acc[it][1] = __builtin_amdgcn_mfma_f32_16x16x32_f16(a.h, b1.h, acc[it][1], 0, 0, 0);
        }
    }
    linv[i] = 1.f / l;   // self-loop guarantees l > 0
    _Float16* obase = seq + (size_t)bt * IN_;
    #pragma unroll
    for (int it = 0; it < 4; ++it) {
        int ib = w*64 + it*16 + G*4;
        #pragma unroll
        for (int ot = 0; ot < 2; ++ot) {
            int o = ot*16 + m;
            float gb = gbv[o];
            #pragma unroll
            for (int r = 0; r < 4; ++r) {
                int row = ib + r;
                obase[row * FOUT + o] = (_Float16)(acc[it][ot][r] * linv[row] + gb);
            }
        }
    }
}

// =====================================================================
// K3: f16 MFMA GEMM  Gp[z][m=bt][n] = A[m][k] * B[n][k] over k-slice z.
// 128x128 tile, BK=32, split-K=8 into SEPARATE partials: plain stores,
// no atomics, no pre-zero. LSTM sums the 8 partials.
// =====================================================================
__global__ __launch_bounds__(256, 4) void gemm_kernel(
    const _Float16* __restrict__ A, const _Float16* __restrict__ Bh,
    float* __restrict__ Gp)
{
    __shared__ __align__(16) _Float16 As[128 * 32];
    __shared__ __align__(16) _Float16 Bs[128 * 32];
    const int t = threadIdx.x;
    const int L = t & 63, w = t >> 6;
    const int wm = w & 1, wn = w >> 1;
    const int m0 = blockIdx.y * 128, n0 = blockIdx.x * 128;
    const int kz = blockIdx.z * 1024;

    f4 acc[4][4] = {};
    const int q0 = t, q1 = t + 256;
    const int row0 = q0 >> 2, kc0 = q0 & 3;
    const int row1 = q1 >> 2, kc1 = q1 & 3;
    const int la = (L & 15) * 32 + (L >> 4) * 8;

    const _Float16* A0 = A + (size_t)(m0 + row0) * IN_ + kz + kc0 * 8;
    const _Float16* A1 = A + (size_t)(m0 + row1) * IN_ + kz + kc1 * 8;
    const _Float16* B0 = Bh + (size_t)(n0 + row0) * IN_ + kz + kc0 * 8;
    const _Float16* B1 = Bh + (size_t)(n0 + row1) * IN_ + kz + kc1 * 8;
    for (int kb = 0; kb < 1024; kb += 32) {
        __syncthreads();
        gload16(A0 + kb, &As[q0 * 8]);
        gload16(A1 + kb, &As[q1 * 8]);
        gload16(B0 + kb, &Bs[q0 * 8]);
        gload16(B1 + kb, &Bs[q1 * 8]);
        __syncthreads();
        half8 af[4], bf[4];
        #pragma unroll
        for (int mi = 0; mi < 4; ++mi)
            af[mi] = *reinterpret_cast<const half8*>(&As[(wm*64 + mi*16) * 32 + la]);
        #pragma unroll
        for (int ni = 0; ni < 4; ++ni)
            bf[ni] = *reinterpret_cast<const half8*>(&Bs[(wn*64 + ni*16) * 32 + la]);
        #pragma unroll
        for (int mi = 0; mi < 4; ++mi)
            #pragma unroll
            for (int ni = 0; ni < 4; ++ni)
                acc[mi][ni] = __builtin_amdgcn_mfma_f32_16x16x32_f16(
                    af[mi], bf[ni], acc[mi][ni], 0, 0, 0);
    }
    float* Gz = Gp + (size_t)blockIdx.z * BT * G4;
    const int cn = n0 + wn * 64 + (L & 15);
    const int rm = m0 + wm * 64 + (L >> 4) * 4;
    #pragma unroll
    for (int mi = 0; mi < 4; ++mi)
        #pragma unroll
        for (int ni = 0; ni < 4; ++ni)
            #pragma unroll
            for (int r = 0; r < 4; ++r)
                Gz[(size_t)(rm + mi*16 + r) * G4 + cn + ni*16] = acc[mi][ni][r];
}

// =====================================================================
// K4: LSTM recurrence + output linear. Block per b, thread = gate row.
// Gate preactivation = bias + sum of 8 split-K partials (prefetched one
// timestep ahead, overlapped with the dot2 chain).
// W_hh row (128 f16x2 packs): 64 VGPR + 32 LDS (128KB) + 32 streamed (L2).
// =====================================================================
__global__ __launch_bounds__(1024) void lstm_kernel(
    const float* __restrict__ Gp, const uint32_t* __restrict__ pwv,
    const uint32_t* __restrict__ pwl, const uint32_t* __restrict__ pws,
    const float* __restrict__ b_ih, const float* __restrict__ b_hh,
    const float* __restrict__ Wo, const float* __restrict__ bo,
    float* __restrict__ out)
{
    const int b = blockIdx.x;
    const int g = threadIdx.x;
    __shared__ __align__(16) uint32_t hsp[128];      // h as f16x2
    __shared__ float gsh[G4];
    __shared__ __align__(16) uint32_t wl[8 * 4096];  // 32 packs x 1024 = 128KB

    uint32_t wv[64];
    #pragma unroll
    for (int p = 0; p < 64; ++p) wv[p] = pwv[p * 1024 + g];
    {
        const uint4* s = reinterpret_cast<const uint4*>(pwl);
        uint4* d = reinterpret_cast<uint4*>(wl);
        #pragma unroll
        for (int r = 0; r < 8; ++r) d[r * 1024 + g] = s[r * 1024 + g];
    }
    if (g < 128) hsp[g] = 0u;
    float c = 0.f;
    const float bias = b_ih[g] + b_hh[g];
    const size_t zs = (size_t)BT * G4;
    const float* Gb = Gp + (size_t)b * T_ * G4 + g;
    const uint4* pws4 = reinterpret_cast<const uint4*>(pws);
    const uint4* wl4  = reinterpret_cast<const uint4*>(wl);
    const uint4* hsp4 = reinterpret_cast<const uint4*>(hsp);

    float gcur = 0.f;
    #pragma unroll
    for (int z = 0; z < KZ; ++z) gcur += Gb[z * zs];
    __syncthreads();

    for (int t = 0; t < T_; ++t) {
        float acc = bias + gcur;
        float pf[KZ];
        const int tn = (t + 1 < T_) ? t + 1 : t;   // harmless dup on last iter
        #pragma unroll
        for (int z = 0; z < KZ; ++z) pf[z] = Gb[(size_t)tn * G4 + z * zs];
        #pragma unroll
        for (int q = 0; q < 32; ++q) {
            uint4 h4 = hsp4[q];
            uint4 w4;
            if (q < 16) {
                w4.x = wv[4*q]; w4.y = wv[4*q+1]; w4.z = wv[4*q+2]; w4.w = wv[4*q+3];
            } else if (q < 24) {
                w4 = wl4[(q - 16) * 1024 + g];
            } else {
                w4 = pws4[(q - 24) * 1024 + g];
            }
            acc = dot2f(w4.x, h4.x, acc);
            acc = dot2f(w4.y, h4.y, acc);
            acc = dot2f(w4.z, h4.z, acc);
            acc = dot2f(w4.w, h4.w, acc);
        }
        gcur = ((pf[0]+pf[1]) + (pf[2]+pf[3])) + ((pf[4]+pf[5]) + (pf[6]+pf[7]));
        gsh[g] = acc;
        __syncthreads();
        if (g < H_) {
            float xi = gsh[g], xf = gsh[H_ + g], xg = gsh[2*H_ + g], xo = gsh[3*H_ + g];
            float si = 1.f / (1.f + __expf(-xi));
            float sf = 1.f / (1.f + __expf(-xf));
            float so = 1.f / (1.f + __expf(-xo));
            float eg = __expf(2.f * xg);
            float tg = 1.f - 2.f / (eg + 1.f);
            c = sf * c + si * tg;
            float ec = __expf(2.f * c);
            float th = 1.f - 2.f / (ec + 1.f);
            reinterpret_cast<_Float16*>(hsp)[g] = (_Float16)(so * th);
        }
        __syncthreads();
    }
    if (g < N_) {
        const float* worow = Wo + (size_t)g * H_;
        float o = bo[g];
        #pragma unroll
        for (int q = 0; q < 32; ++q) {
            uint4 hq = hsp4[q];
            float4 w0 = *reinterpret_cast<const float4*>(worow + q*8);
            float4 w1 = *reinterpret_cast<const float4*>(worow + q*8 + 4);
            o += w0.x * f16lo(hq.x) + w0.y * f16hi(hq.x)
               + w0.z * f16lo(hq.y) + w0.w * f16hi(hq.y)
               + w1.x * f16lo(hq.z) + w1.y * f16hi(hq.z)
               + w1.z * f16lo(hq.w) + w1.w * f16hi(hq.w);
        }
        out[(size_t)b * N_ + g] = o;
    }
}

extern "C" void kernel_launch(void* const* d_in, const int* in_sizes, int n_in,
                              void* d_out, int out_size, void* d_ws, size_t ws_size,
                              hipStream_t stream) {
    const float* x     = (const float*)d_in[0];
    const float* adj   = (const float*)d_in[1];
    const float* W     = (const float*)d_in[2];
    const float* a_src = (const float*)d_in[3];
    const float* a_dst = (const float*)d_in[4];
    const float* gat_b = (const float*)d_in[5];
    const float* W_ih  = (const float*)d_in[6];
    const float* W_hh  = (const float*)d_in[7];
    const float* b_ih  = (const float*)d_in[8];
    const float* b_hh  = (const float*)d_in[9];
    const float* Wo    = (const float*)d_in[10];
    const float* bo    = (const float*)d_in[11];
    float* out = (float*)d_out;

    // ws: seq 16MB | wih_h 16MB | Gp 32MB (8 partials) | pwv 256KB | pwl 128KB | pws 128KB
    _Float16* seq   = (_Float16*)d_ws;
    _Float16* wih_h = seq + (size_t)BT * IN_;
    float*    Gp    = (float*)(wih_h + (size_t)G4 * IN_);
    uint32_t* pwv   = (uint32_t*)(Gp + (size_t)KZ * BT * G4);
    uint32_t* pwl   = pwv + 64 * 1024;
    uint32_t* pws   = pwl + 32 * 1024;

    gat_pack_kernel<<<dim3(NPACK + BT), dim3(256), 0, stream>>>(
        x, adj, W, a_src, a_dst, gat_b, seq, W_ih, W_hh, wih_h, pwv, pwl, pws);
    gemm_kernel<<<dim3(8, 8, KZ), dim3(256), 0, stream>>>(seq, wih_h, Gp);
    lstm_kernel<<<dim3(B_), dim3(1024), 0, stream>>>(Gp, pwv, pwl, pws, b_ih, b_hh, Wo, bo, out);
}